// Round 1
// 1090.723 us; speedup vs baseline: 1.2985x; 1.2985x over previous
//
#include <hip/hip_runtime.h>
#include <cstdint>
#include <cstddef>

typedef __bf16 bf16;
typedef float f32x4 __attribute__((ext_vector_type(4)));
typedef bf16 bf16x8 __attribute__((ext_vector_type(8)));
typedef bf16 bf16x4 __attribute__((ext_vector_type(4)));

#define DM    4096
#define LL    2048
#define BB    2
#define BT    4096      /* B*L */
#define II    4096
#define GN_   1024
#define CONVD 6144
#define PROJD 10304
#define NPAD  10496     /* padded to multiple of 256 for the 256^2 GEMM */
#define HH    64
#define PP    64
#define NN    128
#define CT    64        /* chunk length */
#define NC    32        /* chunks per sequence */

/* ---- output layout (floats) ---- */
#define OUT_OFS_CONV  16777216
#define OUT_OFS_STATE 16814080

/* ---- workspace layout (bytes) ----
   phase 1 (gemm1):  hsb[0,33.5M) winb[33.5M,119.5M)
   phase 2 (scan):   dsb[0,67.1M) overlays dead hsb+winb
   phase 3 (out):    woutb[0,33.5M) ynb[33.5M,67.1M) overlay dead dsb
   always live:      proj, xbc, dtda, ybuf                               */
#define WS_HSB    0UL                   /* bf16 4096x4096      33554432 */
#define WS_WINB   33554432UL            /* bf16 10496x4096     85983232 */
#define WS_DSB    0UL                   /* bf16 [b][h][c][64][128] 67108864 */
#define WS_PROJ   119537664UL           /* f32  4096x10496    171966464 */
#define WS_XBC    291504128UL           /* f32  4096x6144     100663296 */
#define WS_DTDA   392167424UL           /* f32  4096x64x2       2097152 */
#define WS_Y      394264576UL           /* f32  4096x4096      67108864 */
#define WS_WOUTB  0UL                   /* bf16 4096x4096 (after chunkB) */
#define WS_YNB    33554432UL            /* bf16 4096x4096 (after chunkB) */

__device__ __forceinline__ void gl2lds16(const void* g, void* l) {
  __builtin_amdgcn_global_load_lds(
      (__attribute__((address_space(1))) unsigned int*)(uintptr_t)g,
      (__attribute__((address_space(3))) unsigned int*)(uintptr_t)l, 16, 0, 0);
}

/* ---------------- cast fp32 -> bf16 (with zero-pad tail) ---------------- */
__global__ __launch_bounds__(256) void cast_kernel(const float* __restrict__ src,
                                                   bf16* __restrict__ dst,
                                                   long nsrc, long ndst) {
  long i = ((long)blockIdx.x * 256 + threadIdx.x) * 4;
  if (i >= ndst) return;
  bf16x4 o;
  if (i < nsrc) {
    float4 v = *(const float4*)(src + i);
    o[0] = (bf16)v.x; o[1] = (bf16)v.y; o[2] = (bf16)v.z; o[3] = (bf16)v.w;
  } else {
    o[0] = (bf16)0.f; o[1] = (bf16)0.f; o[2] = (bf16)0.f; o[3] = (bf16)0.f;
  }
  *(bf16x4*)(dst + i) = o;
}

/* =====================================================================
   256x256 8-phase bf16 GEMM, C[M,N] = A[M,K] * B[N,K]^T  (C fp32)
   - 512 thr = 8 waves (2M x 4N), per-wave 128x64 out, BK=64
   - LDS 128KiB: sA/sB [2 bufs][256][64], buf0=even K-tiles, buf1=odd
   - XOR swizzle (row&7)<<4 on ds_read addr + pre-swizzled global src
   - counted vmcnt(6) at phases 4/8 only; raw s_barrier (no drain)
   - stage slots (verified WAR-safe, 1 barrier after last reader):
       ph1: B.h1 -> buf1(tile 2i+1)   ph5: B.h1 -> buf0(tile 2i+2)
       ph2: A.h0 -> buf0(tile 2i+2)   ph6: A.h0 -> buf1(tile 2i+3)
       ph3: B.h0 -> buf0               ph7: B.h0 -> buf1
       ph4: A.h1 -> buf0  +vmcnt(6)    ph8: A.h1 -> buf1  +vmcnt(6)
   ===================================================================== */
#define BARF() do { asm volatile("" ::: "memory");                    \
                    __builtin_amdgcn_s_barrier();                     \
                    asm volatile("" ::: "memory"); } while (0)
#define WAITLGKM0() do { asm volatile("s_waitcnt lgkmcnt(0)" ::: "memory"); \
                         __builtin_amdgcn_sched_barrier(0); } while (0)
#define WAITVM(n) asm volatile("s_waitcnt vmcnt(" #n ")" ::: "memory")
#define PRIO1 __builtin_amdgcn_s_setprio(1)
#define PRIO0 __builtin_amdgcn_s_setprio(0)

__device__ __forceinline__ void stage_A_half(const bf16* __restrict__ A, int K,
                                             int arow, int kt, bf16* lds,
                                             int h, int tid) {
  /* half h covers rows {h*64+[0,64), h*64+128+[0,64)} of the 256-row tile */
#pragma unroll
  for (int j = 0; j < 2; ++j) {
    const int r  = h * 64 + j * 128 + (tid >> 3);
    const int cb = (tid & 7) * 16;                 /* linear LDS byte col */
    const int cs = cb ^ ((r & 7) << 4);            /* pre-swizzled source */
    gl2lds16(A + (size_t)(arow + r) * K + kt * 64 + (cs >> 1),
             lds + r * 64 + (cb >> 1));
  }
}
__device__ __forceinline__ void stage_B_half(const bf16* __restrict__ B, int K,
                                             int brow, int kt, bf16* lds,
                                             int h, int tid) {
  /* half h covers rows {q*64 + h*32 + [0,32)} for q=0..3 */
#pragma unroll
  for (int j = 0; j < 2; ++j) {
    const int quarter = j * 2 + (tid >> 8);
    const int kq = tid & 255;
    const int r  = quarter * 64 + h * 32 + (kq >> 3);
    const int cb = (kq & 7) * 16;
    const int cs = cb ^ ((r & 7) << 4);
    gl2lds16(B + (size_t)(brow + r) * K + kt * 64 + (cs >> 1),
             lds + r * 64 + (cb >> 1));
  }
}

#define LDA4(p, mh) do {                                                     \
  _Pragma("unroll") for (int mt = 0; mt < 4; ++mt)                           \
  _Pragma("unroll") for (int kk = 0; kk < 2; ++kk) {                         \
    const int rr = wm * 128 + (mh) * 64 + mt * 16 + l16;                     \
    const int cc = (kk * 64 + quad * 16) ^ ((rr & 7) << 4);                  \
    a_[mt][kk] = *(const bf16x8*)((const char*)(&sA[p][rr][0]) + cc);        \
  } } while (0)

#define LDB2(p, np, barr) do {                                               \
  _Pragma("unroll") for (int nt = 0; nt < 2; ++nt)                           \
  _Pragma("unroll") for (int kk = 0; kk < 2; ++kk) {                         \
    const int rr = wn * 64 + (np) * 32 + nt * 16 + l16;                      \
    const int cc = (kk * 64 + quad * 16) ^ ((rr & 7) << 4);                  \
    barr[nt][kk] = *(const bf16x8*)((const char*)(&sB[p][rr][0]) + cc);      \
  } } while (0)

#define MFMAQ(mh, barr, nb0) do {                                            \
  _Pragma("unroll") for (int kk = 0; kk < 2; ++kk)                           \
  _Pragma("unroll") for (int mt = 0; mt < 4; ++mt)                           \
  _Pragma("unroll") for (int nt = 0; nt < 2; ++nt)                           \
    acc[(mh) * 4 + mt][(nb0) + nt] = __builtin_amdgcn_mfma_f32_16x16x32_bf16(\
        a_[mt][kk], barr[nt][kk], acc[(mh) * 4 + mt][(nb0) + nt], 0, 0, 0);  \
  } while (0)

__global__ __launch_bounds__(512, 2) void gemm256(const bf16* __restrict__ A,
                                                  const bf16* __restrict__ B,
                                                  float* __restrict__ C,
                                                  int M, int N, int K, int NB) {
  __shared__ __align__(16) bf16 sA[2][256][64];
  __shared__ __align__(16) bf16 sB[2][256][64];

  const int tid  = threadIdx.x;
  const int wave = tid >> 6, lane = tid & 63;
  const int l16  = lane & 15, quad = lane >> 4;
  const int wm   = wave >> 2, wn = wave & 3;

  /* bijective XCD swizzle (grid is a multiple of 8) */
  const int nwg = gridDim.x;
  const int q = nwg >> 3, r8 = nwg & 7;
  const int xcd = blockIdx.x & 7, idx = blockIdx.x >> 3;
  const int wgid = (xcd < r8 ? xcd * (q + 1) : r8 * (q + 1) + (xcd - r8) * q) + idx;
  const int mb = wgid / NB, nb = wgid - mb * NB;
  const int arow = mb * 256, brow = nb * 256;

  f32x4 acc[8][4];
#pragma unroll
  for (int i = 0; i < 8; ++i)
#pragma unroll
    for (int j = 0; j < 4; ++j) acc[i][j] = (f32x4)0.f;

  const int NT = K >> 6;   /* 64-wide K tiles; requires K % 128 == 0 */

  /* prologue: tile0 all 4 halves -> buf0, tile1 A0,B0,A1 -> buf1 */
  stage_A_half(A, K, arow, 0, &sA[0][0][0], 0, tid);
  stage_B_half(B, K, brow, 0, &sB[0][0][0], 0, tid);
  stage_A_half(A, K, arow, 0, &sA[0][0][0], 1, tid);
  stage_B_half(B, K, brow, 0, &sB[0][0][0], 1, tid);
  stage_A_half(A, K, arow, 1, &sA[1][0][0], 0, tid);
  stage_B_half(B, K, brow, 1, &sB[1][0][0], 0, tid);
  stage_A_half(A, K, arow, 1, &sA[1][0][0], 1, tid);
  WAITVM(6);
  BARF();

  bf16x8 a_[4][2], b0_[2][2], b1_[2][2];

  for (int i = 0; i < NT / 2; ++i) {
    const int t1o = 2 * i + 1;
    const int t2  = (2 * i + 2 < NT) ? 2 * i + 2 : NT - 1;  /* clamp: staged but never read */
    const int t3  = (2 * i + 3 < NT) ? 2 * i + 3 : NT - 1;

    /* ---- ph1: tile 2i (buf0), quadrant (mh0, np0) ---- */
    LDA4(0, 0); LDB2(0, 0, b0_);
    stage_B_half(B, K, brow, t1o, &sB[1][0][0], 1, tid);
    BARF(); WAITLGKM0();
    PRIO1; MFMAQ(0, b0_, 0); PRIO0;
    BARF();
    /* ---- ph2: (mh0, np1) ---- */
    LDB2(0, 1, b1_);
    stage_A_half(A, K, arow, t2, &sA[0][0][0], 0, tid);
    BARF(); WAITLGKM0();
    PRIO1; MFMAQ(0, b1_, 2); PRIO0;
    BARF();
    /* ---- ph3: (mh1, np1) ---- */
    LDA4(0, 1);
    stage_B_half(B, K, brow, t2, &sB[0][0][0], 0, tid);
    BARF(); WAITLGKM0();
    PRIO1; MFMAQ(1, b1_, 2); PRIO0;
    BARF();
    /* ---- ph4: (mh1, np0), B np0 held since ph1; vmcnt gate for buf1 ---- */
    stage_A_half(A, K, arow, t2, &sA[0][0][0], 1, tid);
    WAITVM(6);
    BARF();
    PRIO1; MFMAQ(1, b0_, 0); PRIO0;
    BARF();
    /* ---- ph5: tile 2i+1 (buf1), (mh0, np0) ---- */
    LDA4(1, 0); LDB2(1, 0, b0_);
    stage_B_half(B, K, brow, t2, &sB[0][0][0], 1, tid);
    BARF(); WAITLGKM0();
    PRIO1; MFMAQ(0, b0_, 0); PRIO0;
    BARF();
    /* ---- ph6: (mh0, np1) ---- */
    LDB2(1, 1, b1_);
    stage_A_half(A, K, arow, t3, &sA[1][0][0], 0, tid);
    BARF(); WAITLGKM0();
    PRIO1; MFMAQ(0, b1_, 2); PRIO0;
    BARF();
    /* ---- ph7: (mh1, np1) ---- */
    LDA4(1, 1);
    stage_B_half(B, K, brow, t3, &sB[1][0][0], 0, tid);
    BARF(); WAITLGKM0();
    PRIO1; MFMAQ(1, b1_, 2); PRIO0;
    BARF();
    /* ---- ph8: (mh1, np0); vmcnt gate for buf0 ---- */
    stage_A_half(A, K, arow, t3, &sA[1][0][0], 1, tid);
    WAITVM(6);
    BARF();
    PRIO1; MFMAQ(1, b0_, 0); PRIO0;
    BARF();
  }
  /* drain dangling prefetches before LDS is released */
  asm volatile("s_waitcnt vmcnt(0)" ::: "memory");
  __builtin_amdgcn_s_barrier();

  /* epilogue: row = wm*128 + mt*16 + quad*4 + r, col = wn*64 + nt*16 + l16 */
#pragma unroll
  for (int mt = 0; mt < 8; ++mt) {
    const int row0 = arow + wm * 128 + mt * 16 + quad * 4;
#pragma unroll
    for (int nt = 0; nt < 4; ++nt) {
      const int col = brow + wn * 64 + nt * 16 + l16;
#pragma unroll
      for (int r = 0; r < 4; ++r)
        C[(size_t)(row0 + r) * N + col] = acc[mt][nt][r];
    }
  }
}

/* ---------------- conv(K=4) + SiLU over hbc slice ----------------------- */
__global__ __launch_bounds__(256) void conv_kernel(const float* __restrict__ proj,
                                                   const float* __restrict__ cw,
                                                   const float* __restrict__ cb,
                                                   float* __restrict__ xbc) {
  const int c  = blockIdx.x * 256 + threadIdx.x;
  const int bt = blockIdx.y;
  const int t  = bt & (LL - 1);
  const float4 w = *(const float4*)(cw + c * 4);
  const float* p = proj + (size_t)bt * NPAD + II + c;
  float acc = cb[c];
  if (t >= 3) {
    acc += p[-3 * (ptrdiff_t)NPAD] * w.x + p[-2 * (ptrdiff_t)NPAD] * w.y
         + p[-(ptrdiff_t)NPAD] * w.z + p[0] * w.w;
  } else {
    const float* pw = &w.x;
    for (int k = 3 - t; k <= 3; ++k)
      acc += p[(ptrdiff_t)(k - 3) * NPAD] * pw[k];
  }
  xbc[(size_t)bt * CONVD + c] = acc / (1.f + __expf(-acc));
}

/* -------- dtda[bt][h] = {softplus(dt+bias), exp(sp * -exp(A_log))} ------ */
__global__ __launch_bounds__(256) void dt_kernel(const float* __restrict__ proj,
                                                 const float* __restrict__ dt_bias,
                                                 const float* __restrict__ A_log,
                                                 float* __restrict__ dtda) {
  const int idx = blockIdx.x * 256 + threadIdx.x;
  const int bt = idx >> 6, h = idx & 63;
  const float z = proj[(size_t)bt * NPAD + (II + CONVD) + h] + dt_bias[h];
  const float sp = (z > 20.f) ? z : log1pf(__expf(z));
  const float a = -__expf(A_log[h]);
  float2 o; o.x = sp; o.y = __expf(sp * a);
  *(float2*)(dtda + (size_t)idx * 2) = o;
}

/* ---------------- conv_state_new = hbc[:, L-3:, :] transposed ----------- */
__global__ __launch_bounds__(256) void convstate_kernel(const float* __restrict__ proj,
                                                        float* __restrict__ outp) {
  const int idx = blockIdx.x * 256 + threadIdx.x;
  if (idx >= BB * CONVD * 3) return;
  const int b = idx / (CONVD * 3);
  const int r = idx - b * CONVD * 3;
  const int c = r / 3, j = r - c * 3;
  outp[idx] = proj[((size_t)b * LL + (LL - 3 + j)) * NPAD + II + c];
}

/* =============== chunked SSD scan =============== */
/* chunkA: per (b,h,c): G=C·B^T, W=mask(G), Yintra=W·X, dS=(wX)^T·B        */
__global__ __launch_bounds__(256) void chunkA_kernel(const float* __restrict__ xbc,
                                                     const float* __restrict__ dtda,
                                                     const float* __restrict__ A_log,
                                                     float* __restrict__ ybuf,
                                                     bf16* __restrict__ dsb) {
  const int h = blockIdx.x, c = blockIdx.y, b = blockIdx.z;
  const int g = h >> 3;
  const int tid = threadIdx.x;
  const int wave = tid >> 6, lane = tid & 63;
  const int l16 = lane & 15, quad = lane >> 4;

  __shared__ __align__(16) bf16 CsBt[8192];
  __shared__ __align__(16) bf16 Bs[64][128];
  __shared__ __align__(16) bf16 Xt[64][64];
  __shared__ __align__(16) bf16 Ws[64][64];
  __shared__ float cums[64], dtps[64], wls[64];

  bf16 (*Cs)[128] = (bf16(*)[128])CsBt;
  bf16 (*Bt)[64]  = (bf16(*)[64])CsBt;

  const size_t rowbase = ((size_t)b * LL + (size_t)c * CT) * CONVD;

  {
    const int i = tid >> 2, col0 = (tid & 3) * 32;
    const float* gpC = xbc + rowbase + (size_t)i * CONVD + (II + GN_) + g * 128 + col0;
    const float* gpB = xbc + rowbase + (size_t)i * CONVD + II + g * 128 + col0;
    const int sx = i & 15;
#pragma unroll
    for (int k = 0; k < 8; ++k) {
      const int n = col0 + k * 4;
      const int eo = (((n >> 3) ^ sx) * 8) + (n & 7);
      float4 v = *(const float4*)(gpC + k * 4);
      bf16x4 o; o[0]=(bf16)v.x; o[1]=(bf16)v.y; o[2]=(bf16)v.z; o[3]=(bf16)v.w;
      *(bf16x4*)(&Cs[i][0] + eo) = o;
      float4 u = *(const float4*)(gpB + k * 4);
      bf16x4 p; p[0]=(bf16)u.x; p[1]=(bf16)u.y; p[2]=(bf16)u.z; p[3]=(bf16)u.w;
      *(bf16x4*)(&Bs[i][0] + eo) = p;
    }
  }
  {
    const int j = tid >> 2, p0 = (tid & 3) * 16;
    const float* gpX = xbc + rowbase + (size_t)j * CONVD + h * 64 + p0;
#pragma unroll
    for (int k = 0; k < 4; ++k) {
      float4 v = *(const float4*)(gpX + k * 4);
      const float* vv = (const float*)&v;
#pragma unroll
      for (int e = 0; e < 4; ++e) {
        const int pp = p0 + k * 4 + e;
        Xt[pp][(((j >> 3) ^ (pp & 7)) * 8) + (j & 7)] = (bf16)vv[e];
      }
    }
  }
  if (wave == 0) {
    const float Ah = -__expf(A_log[h]);
    float2 dd = *(const float2*)(dtda + ((size_t)((b * LL + c * CT + lane)) * 64 + h) * 2);
    float s = dd.x * Ah;
#pragma unroll
    for (int d = 1; d < 64; d <<= 1) {
      float v = __shfl_up(s, d);
      if (lane >= d) s += v;
    }
    const float tot = __shfl(s, 63);
    cums[lane] = s;
    dtps[lane] = dd.x;
    wls[lane]  = __expf(tot - s) * dd.x;
  }
  __syncthreads();

  const int mrow = wave * 16 + l16;
  {
    f32x4 accg[4];
#pragma unroll
    for (int nt = 0; nt < 4; ++nt) accg[nt] = (f32x4)0.f;
#pragma unroll
    for (int k0 = 0; k0 < 128; k0 += 32) {
      bf16x8 af = *(const bf16x8*)&Cs[mrow][(((k0 >> 3) + quad) ^ (mrow & 15)) * 8];
#pragma unroll
      for (int nt = 0; nt < 4; ++nt) {
        const int nrow = nt * 16 + l16;
        bf16x8 bfr = *(const bf16x8*)&Bs[nrow][(((k0 >> 3) + quad) ^ (nrow & 15)) * 8];
        accg[nt] = __builtin_amdgcn_mfma_f32_16x16x32_bf16(af, bfr, accg[nt], 0, 0, 0);
      }
    }
#pragma unroll
    for (int nt = 0; nt < 4; ++nt) {
      const int j = nt * 16 + l16;
#pragma unroll
      for (int r = 0; r < 4; ++r) {
        const int i = wave * 16 + quad * 4 + r;
        float v = 0.f;
        if (j <= i) v = accg[nt][r] * __expf(cums[i] - cums[j]) * dtps[j];
        Ws[i][(((j >> 3) ^ (i & 7)) * 8) + (j & 7)] = (bf16)v;
      }
    }
  }
  __syncthreads();

  {
    const int n = tid >> 1, j0 = (tid & 1) * 32;
#pragma unroll
    for (int jj = 0; jj < 32; ++jj) {
      const int j = j0 + jj;
      bf16 v = Bs[j][(((n >> 3) ^ (j & 15)) * 8) + (n & 7)];
      Bt[n][(((j >> 3) ^ (n & 7)) * 8) + (j & 7)] = v;
    }
  }
  __syncthreads();

  f32x4 accy[4];
#pragma unroll
  for (int pt = 0; pt < 4; ++pt) accy[pt] = (f32x4)0.f;
#pragma unroll
  for (int k0 = 0; k0 < 64; k0 += 32) {
    bf16x8 af = *(const bf16x8*)&Ws[mrow][(((k0 >> 3) + quad) ^ (mrow & 7)) * 8];
#pragma unroll
    for (int pt = 0; pt < 4; ++pt) {
      const int prow = pt * 16 + l16;
      bf16x8 bfr = *(const bf16x8*)&Xt[prow][(((k0 >> 3) + quad) ^ (prow & 7)) * 8];
      accy[pt] = __builtin_amdgcn_mfma_f32_16x16x32_bf16(af, bfr, accy[pt], 0, 0, 0);
    }
  }

  f32x4 accs[8];
#pragma unroll
  for (int nt = 0; nt < 8; ++nt) accs[nt] = (f32x4)0.f;
#pragma unroll
  for (int k0 = 0; k0 < 64; k0 += 32) {
    bf16x8 axr = *(const bf16x8*)&Xt[mrow][(((k0 >> 3) + quad) ^ (mrow & 7)) * 8];
    bf16x8 ax;
#pragma unroll
    for (int e = 0; e < 8; ++e)
      ax[e] = (bf16)((float)axr[e] * wls[k0 + quad * 8 + e]);
#pragma unroll
    for (int nt = 0; nt < 8; ++nt) {
      const int nrow = nt * 16 + l16;
      bf16x8 bfr = *(const bf16x8*)&Bt[nrow][(((k0 >> 3) + quad) ^ (nrow & 7)) * 8];
      accs[nt] = __builtin_amdgcn_mfma_f32_16x16x32_bf16(ax, bfr, accs[nt], 0, 0, 0);
    }
  }

#pragma unroll
  for (int pt = 0; pt < 4; ++pt) {
#pragma unroll
    for (int r = 0; r < 4; ++r) {
      const int i = wave * 16 + quad * 4 + r;
      ybuf[((size_t)(b * LL + c * CT + i)) * II + h * 64 + pt * 16 + l16] = accy[pt][r];
    }
  }
  const size_t dbase = (((size_t)(b * HH + h)) * NC + c) * (CT * NN);
#pragma unroll
  for (int nt = 0; nt < 8; ++nt) {
#pragma unroll
    for (int r = 0; r < 4; ++r) {
      const int p = wave * 16 + quad * 4 + r;
      dsb[dbase + (size_t)p * NN + nt * 16 + l16] = (bf16)accs[nt][r];
    }
  }
}

/* chain: serial over 32 chunks; in-place dS -> S_prev; final_state -> out */
__global__ __launch_bounds__(256) void chain_kernel(const float* __restrict__ dtda,
                                                    const float* __restrict__ A_log,
                                                    bf16* __restrict__ dsb,
                                                    float* __restrict__ fst) {
  const int blk = blockIdx.x;
  const int b = blk >> 7, h = (blk >> 1) & 63, half = blk & 1;
  const int tid = threadIdx.x, wave = tid >> 6, lane = tid & 63;
  __shared__ float DcL[NC];

  const float Ah = -__expf(A_log[h]);
#pragma unroll
  for (int cc = 0; cc < 8; ++cc) {
    const int c = wave * 8 + cc;
    float2 dd = *(const float2*)(dtda + ((size_t)(b * LL + c * CT + lane) * 64 + h) * 2);
    float a = dd.x * Ah;
#pragma unroll
    for (int m = 1; m <= 32; m <<= 1) a += __shfl_xor(a, m);
    if (lane == 0) DcL[c] = __expf(a);
  }
  __syncthreads();

  const int local = half * 4096 + tid * 16;
  const size_t base = ((size_t)(b * HH + h)) * NC * (CT * NN) + local;
  float s[16];
#pragma unroll
  for (int e = 0; e < 16; ++e) s[e] = 0.f;

  for (int c = 0; c < NC; ++c) {
    bf16* p = dsb + base + (size_t)c * (CT * NN);
    bf16x8 d0 = *(const bf16x8*)(p);
    bf16x8 d1 = *(const bf16x8*)(p + 8);
    const float dc = DcL[c];
    bf16x8 o0, o1;
#pragma unroll
    for (int e = 0; e < 8; ++e) { o0[e] = (bf16)s[e]; o1[e] = (bf16)s[8 + e]; }
    *(bf16x8*)(p)     = o0;
    *(bf16x8*)(p + 8) = o1;
#pragma unroll
    for (int e = 0; e < 8; ++e) {
      s[e]     = s[e] * dc + (float)d0[e];
      s[8 + e] = s[8 + e] * dc + (float)d1[e];
    }
  }
  float* fp = fst + ((size_t)(b * HH + h)) * (PP * NN) + local;
#pragma unroll
  for (int k = 0; k < 4; ++k) {
    float4 v = { s[k * 4], s[k * 4 + 1], s[k * 4 + 2], s[k * 4 + 3] };
    *(float4*)(fp + k * 4) = v;
  }
}

/* chunkB: y = Yintra + exp(cum_i)*(C·S_prev^T) + D*x */
__global__ __launch_bounds__(256) void chunkB_kernel(const float* __restrict__ xbc,
                                                     const float* __restrict__ dtda,
                                                     const float* __restrict__ A_log,
                                                     const float* __restrict__ Dv,
                                                     const bf16* __restrict__ spb,
                                                     float* __restrict__ ybuf) {
  const int h = blockIdx.x, c = blockIdx.y, b = blockIdx.z;
  const int g = h >> 3;
  const int tid = threadIdx.x;
  const int wave = tid >> 6, lane = tid & 63;
  const int l16 = lane & 15, quad = lane >> 4;

  __shared__ __align__(16) bf16 Cs[64][128];
  __shared__ __align__(16) bf16 Sp[64][128];
  __shared__ float es[64];

  const size_t rowbase = ((size_t)b * LL + (size_t)c * CT) * CONVD;
  {
    const int i = tid >> 2, col0 = (tid & 3) * 32;
    const float* gpC = xbc + rowbase + (size_t)i * CONVD + (II + GN_) + g * 128 + col0;
    const int sx = i & 15;
#pragma unroll
    for (int k = 0; k < 8; ++k) {
      const int n = col0 + k * 4;
      float4 v = *(const float4*)(gpC + k * 4);
      bf16x4 o; o[0]=(bf16)v.x; o[1]=(bf16)v.y; o[2]=(bf16)v.z; o[3]=(bf16)v.w;
      *(bf16x4*)(&Cs[i][0] + (((n >> 3) ^ sx) * 8) + (n & 7)) = o;
    }
  }
  {
    const int p = tid >> 2, nseg = (tid & 3) * 32;
    const bf16* gp = spb + (((size_t)(b * HH + h)) * NC + c) * (CT * NN) + (size_t)p * NN + nseg;
    const int sx = p & 15;
#pragma unroll
    for (int k = 0; k < 4; ++k) {
      const int n0 = nseg + k * 8;
      bf16x8 v = *(const bf16x8*)(gp + k * 8);
      *(bf16x8*)(&Sp[p][0] + (((n0 >> 3) ^ sx) * 8)) = v;
    }
  }
  if (wave == 0) {
    const float Ah = -__expf(A_log[h]);
    float2 dd = *(const float2*)(dtda + ((size_t)(b * LL + c * CT + lane) * 64 + h) * 2);
    float s = dd.x * Ah;
#pragma unroll
    for (int d = 1; d < 64; d <<= 1) {
      float v = __shfl_up(s, d);
      if (lane >= d) s += v;
    }
    es[lane] = __expf(s);
  }
  __syncthreads();

  const int mrow = wave * 16 + l16;
  f32x4 acc[4];
#pragma unroll
  for (int pt = 0; pt < 4; ++pt) acc[pt] = (f32x4)0.f;
#pragma unroll
  for (int k0 = 0; k0 < 128; k0 += 32) {
    bf16x8 af = *(const bf16x8*)&Cs[mrow][(((k0 >> 3) + quad) ^ (mrow & 15)) * 8];
#pragma unroll
    for (int pt = 0; pt < 4; ++pt) {
      const int prow = pt * 16 + l16;
      bf16x8 bfr = *(const bf16x8*)&Sp[prow][(((k0 >> 3) + quad) ^ (prow & 15)) * 8];
      acc[pt] = __builtin_amdgcn_mfma_f32_16x16x32_bf16(af, bfr, acc[pt], 0, 0, 0);
    }
  }

  const float Dh = Dv[h];
#pragma unroll
  for (int pt = 0; pt < 4; ++pt) {
#pragma unroll
    for (int r = 0; r < 4; ++r) {
      const int i = wave * 16 + quad * 4 + r;
      const int p = pt * 16 + l16;
      const size_t row = (size_t)(b * LL + c * CT + i);
      const size_t ya = row * II + h * 64 + p;
      const float xv = xbc[row * CONVD + h * 64 + p];
      ybuf[ya] = acc[pt][r] * es[i] + ybuf[ya] + Dh * xv;
    }
  }
}

/* ---------------- groupnorm(512) * silu(gate) -> bf16 ------------------- */
__global__ __launch_bounds__(256) void norm_kernel(const float* __restrict__ y,
                                                   const float* __restrict__ proj,
                                                   const float* __restrict__ nw,
                                                   bf16* __restrict__ yn) {
  const int bt = blockIdx.x, tid = threadIdx.x;
  const float* yr = y + (size_t)bt * II + tid * 16;
  float4 v[4];
  float ss = 0.f;
#pragma unroll
  for (int i = 0; i < 4; ++i) {
    v[i] = *(const float4*)(yr + i * 4);
    ss += v[i].x * v[i].x + v[i].y * v[i].y + v[i].z * v[i].z + v[i].w * v[i].w;
  }
#pragma unroll
  for (int m = 1; m <= 16; m <<= 1) ss += __shfl_xor(ss, m);
  const float rstd = rsqrtf(ss * (1.f / 512.f) + 1e-5f);

  const float* gr  = proj + (size_t)bt * NPAD + tid * 16;
  const float* nwr = nw + tid * 16;
  bf16x8 o0, o1;
#pragma unroll
  for (int i = 0; i < 4; ++i) {
    float4 gv = *(const float4*)(gr + i * 4);
    float4 nv = *(const float4*)(nwr + i * 4);
    const float* vv = (const float*)&v[i];
    const float* gg = (const float*)&gv;
    const float* nn = (const float*)&nv;
#pragma unroll
    for (int j = 0; j < 4; ++j) {
      const float gate = gg[j];
      const float val = vv[j] * rstd * nn[j] * (gate / (1.f + __expf(-gate)));
      if (i < 2) o0[i * 4 + j] = (bf16)val;
      else       o1[(i - 2) * 4 + j] = (bf16)val;
    }
  }
  bf16* dst = yn + (size_t)bt * II + tid * 16;
  *(bf16x8*)(dst)     = o0;
  *(bf16x8*)(dst + 8) = o1;
}

extern "C" void kernel_launch(void* const* d_in, const int* in_sizes, int n_in,
                              void* d_out, int out_size, void* d_ws, size_t ws_size,
                              hipStream_t stream) {
  const float* hs      = (const float*)d_in[0];
  const float* w_in    = (const float*)d_in[1];
  const float* cw      = (const float*)d_in[2];
  const float* cb      = (const float*)d_in[3];
  const float* dt_bias = (const float*)d_in[4];
  const float* A_log   = (const float*)d_in[5];
  const float* Dv      = (const float*)d_in[6];
  const float* nw      = (const float*)d_in[7];
  const float* w_out   = (const float*)d_in[8];

  char* ws = (char*)d_ws;
  bf16*  hsb   = (bf16*)(ws + WS_HSB);
  bf16*  winb  = (bf16*)(ws + WS_WINB);
  bf16*  dsb   = (bf16*)(ws + WS_DSB);
  float* proj  = (float*)(ws + WS_PROJ);
  float* xbc   = (float*)(ws + WS_XBC);
  float* dtda  = (float*)(ws + WS_DTDA);
  float* ybuf  = (float*)(ws + WS_Y);
  bf16*  ynb   = (bf16*)(ws + WS_YNB);
  bf16*  woutb = (bf16*)(ws + WS_WOUTB);

  float* outp = (float*)d_out;

  cast_kernel<<<16384, 256, 0, stream>>>(hs, hsb, 16777216L, 16777216L);
  cast_kernel<<<41984, 256, 0, stream>>>(w_in, winb, (long)PROJD * DM, (long)NPAD * DM);

  gemm256<<<(BT / 256) * (NPAD / 256), 512, 0, stream>>>(hsb, winb, proj, BT, NPAD, DM, NPAD / 256);

  conv_kernel<<<dim3(CONVD / 256, BT), 256, 0, stream>>>(proj, cw, cb, xbc);
  dt_kernel<<<(BT * HH) / 256, 256, 0, stream>>>(proj, dt_bias, A_log, dtda);
  convstate_kernel<<<(BB * CONVD * 3 + 255) / 256, 256, 0, stream>>>(proj, outp + OUT_OFS_CONV);

  chunkA_kernel<<<dim3(HH, NC, BB), 256, 0, stream>>>(xbc, dtda, A_log, ybuf, dsb);
  chain_kernel<<<BB * HH * 2, 256, 0, stream>>>(dtda, A_log, dsb, outp + OUT_OFS_STATE);
  chunkB_kernel<<<dim3(HH, NC, BB), 256, 0, stream>>>(xbc, dtda, A_log, Dv, dsb, ybuf);

  /* w_out cast deferred here so woutb/ynb can overlay the dead hsb/winb/dsb region */
  cast_kernel<<<16384, 256, 0, stream>>>(w_out, woutb, 16777216L, 16777216L);
  norm_kernel<<<BT, 256, 0, stream>>>(ybuf, proj, nw, ynb);

  gemm256<<<(BT / 256) * (DM / 256), 512, 0, stream>>>(ynb, woutb, outp, BT, DM, II, DM / 256);
}

// Round 2
// 974.163 us; speedup vs baseline: 1.4539x; 1.1197x over previous
//
#include <hip/hip_runtime.h>
#include <cstdint>
#include <cstddef>

typedef __bf16 bf16;
typedef float f32x4 __attribute__((ext_vector_type(4)));
typedef bf16 bf16x8 __attribute__((ext_vector_type(8)));
typedef bf16 bf16x4 __attribute__((ext_vector_type(4)));

#define DM    4096
#define LL    2048
#define BB    2
#define BT    4096      /* B*L */
#define II    4096
#define GN_   1024
#define CONVD 6144
#define PROJD 10304
#define NPAD  10496     /* padded to multiple of 256 for the 256^2 GEMM */
#define HH    64
#define PP    64
#define NN    128
#define CT    64        /* chunk length */
#define NC    32        /* chunks per sequence */

/* ---- output layout (floats) ---- */
#define OUT_OFS_CONV  16777216
#define OUT_OFS_STATE 16814080

/* ---- workspace layout (bytes) ----
   phase 1 (gemm1):  hsb[0,33.5M) winb[33.5M,119.5M)
   phase 2 (scan):   dsb[0,67.1M) overlays dead hsb+winb
   phase 3 (out):    woutb[0,33.5M) ynb[33.5M,67.1M) overlay dead dsb
   always live:      proj, xbc(bf16), dtda, ybuf                         */
#define WS_HSB    0UL                   /* bf16 4096x4096      33554432 */
#define WS_WINB   33554432UL            /* bf16 10496x4096     85983232 */
#define WS_DSB    0UL                   /* bf16 [b][h][c][64][128] 67108864 */
#define WS_PROJ   119537664UL           /* f32  4096x10496    171966464 */
#define WS_XBC    291504128UL           /* bf16 4096x6144      50331648 */
#define WS_DTDA   392167424UL           /* f32  4096x64x2       2097152 */
#define WS_Y      394264576UL           /* f32  4096x4096      67108864 */
#define WS_WOUTB  0UL                   /* bf16 4096x4096 (after chunkB) */
#define WS_YNB    33554432UL            /* bf16 4096x4096 (after chunkB) */

__device__ __forceinline__ void gl2lds16(const void* g, void* l) {
  __builtin_amdgcn_global_load_lds(
      (__attribute__((address_space(1))) unsigned int*)(uintptr_t)g,
      (__attribute__((address_space(3))) unsigned int*)(uintptr_t)l, 16, 0, 0);
}

/* ---------------- cast fp32 -> bf16 (with zero-pad tail) ---------------- */
__global__ __launch_bounds__(256) void cast_kernel(const float* __restrict__ src,
                                                   bf16* __restrict__ dst,
                                                   long nsrc, long ndst) {
  long i = ((long)blockIdx.x * 256 + threadIdx.x) * 4;
  if (i >= ndst) return;
  bf16x4 o;
  if (i < nsrc) {
    float4 v = *(const float4*)(src + i);
    o[0] = (bf16)v.x; o[1] = (bf16)v.y; o[2] = (bf16)v.z; o[3] = (bf16)v.w;
  } else {
    o[0] = (bf16)0.f; o[1] = (bf16)0.f; o[2] = (bf16)0.f; o[3] = (bf16)0.f;
  }
  *(bf16x4*)(dst + i) = o;
}

/* =====================================================================
   256x256 8-phase bf16 GEMM, C[M,N] = A[M,K] * B[N,K]^T  (C fp32)
   (unchanged from round 1: 1000 TF, 0 bank conflicts)
   ===================================================================== */
#define BARF() do { asm volatile("" ::: "memory");                    \
                    __builtin_amdgcn_s_barrier();                     \
                    asm volatile("" ::: "memory"); } while (0)
#define WAITLGKM0() do { asm volatile("s_waitcnt lgkmcnt(0)" ::: "memory"); \
                         __builtin_amdgcn_sched_barrier(0); } while (0)
#define WAITVM(n) asm volatile("s_waitcnt vmcnt(" #n ")" ::: "memory")
#define PRIO1 __builtin_amdgcn_s_setprio(1)
#define PRIO0 __builtin_amdgcn_s_setprio(0)

__device__ __forceinline__ void stage_A_half(const bf16* __restrict__ A, int K,
                                             int arow, int kt, bf16* lds,
                                             int h, int tid) {
#pragma unroll
  for (int j = 0; j < 2; ++j) {
    const int r  = h * 64 + j * 128 + (tid >> 3);
    const int cb = (tid & 7) * 16;
    const int cs = cb ^ ((r & 7) << 4);
    gl2lds16(A + (size_t)(arow + r) * K + kt * 64 + (cs >> 1),
             lds + r * 64 + (cb >> 1));
  }
}
__device__ __forceinline__ void stage_B_half(const bf16* __restrict__ B, int K,
                                             int brow, int kt, bf16* lds,
                                             int h, int tid) {
#pragma unroll
  for (int j = 0; j < 2; ++j) {
    const int quarter = j * 2 + (tid >> 8);
    const int kq = tid & 255;
    const int r  = quarter * 64 + h * 32 + (kq >> 3);
    const int cb = (kq & 7) * 16;
    const int cs = cb ^ ((r & 7) << 4);
    gl2lds16(B + (size_t)(brow + r) * K + kt * 64 + (cs >> 1),
             lds + r * 64 + (cb >> 1));
  }
}

#define LDA4(p, mh) do {                                                     \
  _Pragma("unroll") for (int mt = 0; mt < 4; ++mt)                           \
  _Pragma("unroll") for (int kk = 0; kk < 2; ++kk) {                         \
    const int rr = wm * 128 + (mh) * 64 + mt * 16 + l16;                     \
    const int cc = (kk * 64 + quad * 16) ^ ((rr & 7) << 4);                  \
    a_[mt][kk] = *(const bf16x8*)((const char*)(&sA[p][rr][0]) + cc);        \
  } } while (0)

#define LDB2(p, np, barr) do {                                               \
  _Pragma("unroll") for (int nt = 0; nt < 2; ++nt)                           \
  _Pragma("unroll") for (int kk = 0; kk < 2; ++kk) {                         \
    const int rr = wn * 64 + (np) * 32 + nt * 16 + l16;                      \
    const int cc = (kk * 64 + quad * 16) ^ ((rr & 7) << 4);                  \
    barr[nt][kk] = *(const bf16x8*)((const char*)(&sB[p][rr][0]) + cc);      \
  } } while (0)

#define MFMAQ(mh, barr, nb0) do {                                            \
  _Pragma("unroll") for (int kk = 0; kk < 2; ++kk)                           \
  _Pragma("unroll") for (int mt = 0; mt < 4; ++mt)                           \
  _Pragma("unroll") for (int nt = 0; nt < 2; ++nt)                           \
    acc[(mh) * 4 + mt][(nb0) + nt] = __builtin_amdgcn_mfma_f32_16x16x32_bf16(\
        a_[mt][kk], barr[nt][kk], acc[(mh) * 4 + mt][(nb0) + nt], 0, 0, 0);  \
  } while (0)

__global__ __launch_bounds__(512, 2) void gemm256(const bf16* __restrict__ A,
                                                  const bf16* __restrict__ B,
                                                  float* __restrict__ C,
                                                  int M, int N, int K, int NB) {
  __shared__ __align__(16) bf16 sA[2][256][64];
  __shared__ __align__(16) bf16 sB[2][256][64];

  const int tid  = threadIdx.x;
  const int wave = tid >> 6, lane = tid & 63;
  const int l16  = lane & 15, quad = lane >> 4;
  const int wm   = wave >> 2, wn = wave & 3;

  const int nwg = gridDim.x;
  const int q = nwg >> 3, r8 = nwg & 7;
  const int xcd = blockIdx.x & 7, idx = blockIdx.x >> 3;
  const int wgid = (xcd < r8 ? xcd * (q + 1) : r8 * (q + 1) + (xcd - r8) * q) + idx;
  const int mb = wgid / NB, nb = wgid - mb * NB;
  const int arow = mb * 256, brow = nb * 256;

  f32x4 acc[8][4];
#pragma unroll
  for (int i = 0; i < 8; ++i)
#pragma unroll
    for (int j = 0; j < 4; ++j) acc[i][j] = (f32x4)0.f;

  const int NT = K >> 6;

  stage_A_half(A, K, arow, 0, &sA[0][0][0], 0, tid);
  stage_B_half(B, K, brow, 0, &sB[0][0][0], 0, tid);
  stage_A_half(A, K, arow, 0, &sA[0][0][0], 1, tid);
  stage_B_half(B, K, brow, 0, &sB[0][0][0], 1, tid);
  stage_A_half(A, K, arow, 1, &sA[1][0][0], 0, tid);
  stage_B_half(B, K, brow, 1, &sB[1][0][0], 0, tid);
  stage_A_half(A, K, arow, 1, &sA[1][0][0], 1, tid);
  WAITVM(6);
  BARF();

  bf16x8 a_[4][2], b0_[2][2], b1_[2][2];

  for (int i = 0; i < NT / 2; ++i) {
    const int t1o = 2 * i + 1;
    const int t2  = (2 * i + 2 < NT) ? 2 * i + 2 : NT - 1;
    const int t3  = (2 * i + 3 < NT) ? 2 * i + 3 : NT - 1;

    LDA4(0, 0); LDB2(0, 0, b0_);
    stage_B_half(B, K, brow, t1o, &sB[1][0][0], 1, tid);
    BARF(); WAITLGKM0();
    PRIO1; MFMAQ(0, b0_, 0); PRIO0;
    BARF();
    LDB2(0, 1, b1_);
    stage_A_half(A, K, arow, t2, &sA[0][0][0], 0, tid);
    BARF(); WAITLGKM0();
    PRIO1; MFMAQ(0, b1_, 2); PRIO0;
    BARF();
    LDA4(0, 1);
    stage_B_half(B, K, brow, t2, &sB[0][0][0], 0, tid);
    BARF(); WAITLGKM0();
    PRIO1; MFMAQ(1, b1_, 2); PRIO0;
    BARF();
    stage_A_half(A, K, arow, t2, &sA[0][0][0], 1, tid);
    WAITVM(6);
    BARF();
    PRIO1; MFMAQ(1, b0_, 0); PRIO0;
    BARF();
    LDA4(1, 0); LDB2(1, 0, b0_);
    stage_B_half(B, K, brow, t2, &sB[0][0][0], 1, tid);
    BARF(); WAITLGKM0();
    PRIO1; MFMAQ(0, b0_, 0); PRIO0;
    BARF();
    LDB2(1, 1, b1_);
    stage_A_half(A, K, arow, t3, &sA[1][0][0], 0, tid);
    BARF(); WAITLGKM0();
    PRIO1; MFMAQ(0, b1_, 2); PRIO0;
    BARF();
    LDA4(1, 1);
    stage_B_half(B, K, brow, t3, &sB[1][0][0], 0, tid);
    BARF(); WAITLGKM0();
    PRIO1; MFMAQ(1, b1_, 2); PRIO0;
    BARF();
    stage_A_half(A, K, arow, t3, &sA[1][0][0], 1, tid);
    WAITVM(6);
    BARF();
    PRIO1; MFMAQ(1, b0_, 0); PRIO0;
    BARF();
  }
  asm volatile("s_waitcnt vmcnt(0)" ::: "memory");
  __builtin_amdgcn_s_barrier();

#pragma unroll
  for (int mt = 0; mt < 8; ++mt) {
    const int row0 = arow + wm * 128 + mt * 16 + quad * 4;
#pragma unroll
    for (int nt = 0; nt < 4; ++nt) {
      const int col = brow + wn * 64 + nt * 16 + l16;
#pragma unroll
      for (int r = 0; r < 4; ++r)
        C[(size_t)(row0 + r) * N + col] = acc[mt][nt][r];
    }
  }
}

/* ---------------- conv(K=4) + SiLU, rolling-window, bf16 out ------------ */
/* thread = one channel; block = 256 channels x 64 rows. Reads each proj
   row once (4x less than tap-per-output), writes bf16 xbc (2x less).    */
#define CTILE 64
__global__ __launch_bounds__(256) void conv_kernel(const float* __restrict__ proj,
                                                   const float* __restrict__ cw,
                                                   const float* __restrict__ cb,
                                                   bf16* __restrict__ xbc) {
  const int c   = blockIdx.x * 256 + threadIdx.x;
  const int bt0 = blockIdx.y * CTILE;
  const int t0  = bt0 & (LL - 1);
  const float4 w = *(const float4*)(cw + c * 4);
  const float bias = cb[c];
  const float* p = proj + (size_t)bt0 * NPAD + II + c;
  float h0, h1, h2;
  if (t0 == 0) {
    h0 = 0.f; h1 = 0.f; h2 = 0.f;
  } else {
    h0 = p[-3 * (ptrdiff_t)NPAD];
    h1 = p[-2 * (ptrdiff_t)NPAD];
    h2 = p[-(ptrdiff_t)NPAD];
  }
  bf16* q = xbc + (size_t)bt0 * CONVD + c;
#pragma unroll 8
  for (int t = 0; t < CTILE; ++t) {
    const float cur = p[(ptrdiff_t)t * NPAD];
    const float acc = bias + h0 * w.x + h1 * w.y + h2 * w.z + cur * w.w;
    q[(size_t)t * CONVD] = (bf16)(acc / (1.f + __expf(-acc)));
    h0 = h1; h1 = h2; h2 = cur;
  }
}

/* -------- dtda[bt][h] = {softplus(dt+bias), exp(sp * -exp(A_log))} ------ */
__global__ __launch_bounds__(256) void dt_kernel(const float* __restrict__ proj,
                                                 const float* __restrict__ dt_bias,
                                                 const float* __restrict__ A_log,
                                                 float* __restrict__ dtda) {
  const int idx = blockIdx.x * 256 + threadIdx.x;
  const int bt = idx >> 6, h = idx & 63;
  const float z = proj[(size_t)bt * NPAD + (II + CONVD) + h] + dt_bias[h];
  const float sp = (z > 20.f) ? z : log1pf(__expf(z));
  const float a = -__expf(A_log[h]);
  float2 o; o.x = sp; o.y = __expf(sp * a);
  *(float2*)(dtda + (size_t)idx * 2) = o;
}

/* ---------------- conv_state_new = hbc[:, L-3:, :] transposed ----------- */
__global__ __launch_bounds__(256) void convstate_kernel(const float* __restrict__ proj,
                                                        float* __restrict__ outp) {
  const int idx = blockIdx.x * 256 + threadIdx.x;
  if (idx >= BB * CONVD * 3) return;
  const int b = idx / (CONVD * 3);
  const int r = idx - b * CONVD * 3;
  const int c = r / 3, j = r - c * 3;
  outp[idx] = proj[((size_t)b * LL + (LL - 3 + j)) * NPAD + II + c];
}

/* =============== chunked SSD scan =============== */
/* chunkA: per (b,h,c): G=C·B^T, W=mask(G), Yintra=W·X, dS=(wX)^T·B        */
__global__ __launch_bounds__(256) void chunkA_kernel(const bf16* __restrict__ xbc,
                                                     const float* __restrict__ dtda,
                                                     const float* __restrict__ A_log,
                                                     float* __restrict__ ybuf,
                                                     bf16* __restrict__ dsb) {
  const int h = blockIdx.x, c = blockIdx.y, b = blockIdx.z;
  const int g = h >> 3;
  const int tid = threadIdx.x;
  const int wave = tid >> 6, lane = tid & 63;
  const int l16 = lane & 15, quad = lane >> 4;

  __shared__ __align__(16) bf16 CsBt[8192];
  __shared__ __align__(16) bf16 Bs[64][128];
  __shared__ __align__(16) bf16 Xt[64][64];
  __shared__ __align__(16) bf16 Ws[64][64];
  __shared__ float cums[64], dtps[64], wls[64];

  bf16 (*Cs)[128] = (bf16(*)[128])CsBt;
  bf16 (*Bt)[64]  = (bf16(*)[64])CsBt;

  const size_t rowbase = ((size_t)b * LL + (size_t)c * CT) * CONVD;

  {
    const int i = tid >> 2, col0 = (tid & 3) * 32;
    const bf16* gpC = xbc + rowbase + (size_t)i * CONVD + (II + GN_) + g * 128 + col0;
    const bf16* gpB = xbc + rowbase + (size_t)i * CONVD + II + g * 128 + col0;
    const int sx = i & 15;
#pragma unroll
    for (int k = 0; k < 4; ++k) {
      const int n0 = col0 + k * 8;
      const int eo = ((n0 >> 3) ^ sx) * 8;
      *(bf16x8*)(&Cs[i][0] + eo) = *(const bf16x8*)(gpC + k * 8);
      *(bf16x8*)(&Bs[i][0] + eo) = *(const bf16x8*)(gpB + k * 8);
    }
  }
  {
    const int j = tid >> 2, p0 = (tid & 3) * 16;
    const bf16* gpX = xbc + rowbase + (size_t)j * CONVD + h * 64 + p0;
#pragma unroll
    for (int k = 0; k < 2; ++k) {
      bf16x8 v = *(const bf16x8*)(gpX + k * 8);
#pragma unroll
      for (int e = 0; e < 8; ++e) {
        const int pp = p0 + k * 8 + e;
        Xt[pp][(((j >> 3) ^ (pp & 7)) * 8) + (j & 7)] = v[e];
      }
    }
  }
  if (wave == 0) {
    const float Ah = -__expf(A_log[h]);
    float2 dd = *(const float2*)(dtda + ((size_t)((b * LL + c * CT + lane)) * 64 + h) * 2);
    float s = dd.x * Ah;
#pragma unroll
    for (int d = 1; d < 64; d <<= 1) {
      float v = __shfl_up(s, d);
      if (lane >= d) s += v;
    }
    const float tot = __shfl(s, 63);
    cums[lane] = s;
    dtps[lane] = dd.x;
    wls[lane]  = __expf(tot - s) * dd.x;
  }
  __syncthreads();

  const int mrow = wave * 16 + l16;
  {
    f32x4 accg[4];
#pragma unroll
    for (int nt = 0; nt < 4; ++nt) accg[nt] = (f32x4)0.f;
#pragma unroll
    for (int k0 = 0; k0 < 128; k0 += 32) {
      bf16x8 af = *(const bf16x8*)&Cs[mrow][(((k0 >> 3) + quad) ^ (mrow & 15)) * 8];
#pragma unroll
      for (int nt = 0; nt < 4; ++nt) {
        const int nrow = nt * 16 + l16;
        bf16x8 bfr = *(const bf16x8*)&Bs[nrow][(((k0 >> 3) + quad) ^ (nrow & 15)) * 8];
        accg[nt] = __builtin_amdgcn_mfma_f32_16x16x32_bf16(af, bfr, accg[nt], 0, 0, 0);
      }
    }
#pragma unroll
    for (int nt = 0; nt < 4; ++nt) {
      const int j = nt * 16 + l16;
#pragma unroll
      for (int r = 0; r < 4; ++r) {
        const int i = wave * 16 + quad * 4 + r;
        float v = 0.f;
        if (j <= i) v = accg[nt][r] * __expf(cums[i] - cums[j]) * dtps[j];
        Ws[i][(((j >> 3) ^ (i & 7)) * 8) + (j & 7)] = (bf16)v;
      }
    }
  }
  __syncthreads();

  {
    const int n = tid >> 1, j0 = (tid & 1) * 32;
#pragma unroll
    for (int jj = 0; jj < 32; ++jj) {
      const int j = j0 + jj;
      bf16 v = Bs[j][(((n >> 3) ^ (j & 15)) * 8) + (n & 7)];
      Bt[n][(((j >> 3) ^ (n & 7)) * 8) + (j & 7)] = v;
    }
  }
  __syncthreads();

  f32x4 accy[4];
#pragma unroll
  for (int pt = 0; pt < 4; ++pt) accy[pt] = (f32x4)0.f;
#pragma unroll
  for (int k0 = 0; k0 < 64; k0 += 32) {
    bf16x8 af = *(const bf16x8*)&Ws[mrow][(((k0 >> 3) + quad) ^ (mrow & 7)) * 8];
#pragma unroll
    for (int pt = 0; pt < 4; ++pt) {
      const int prow = pt * 16 + l16;
      bf16x8 bfr = *(const bf16x8*)&Xt[prow][(((k0 >> 3) + quad) ^ (prow & 7)) * 8];
      accy[pt] = __builtin_amdgcn_mfma_f32_16x16x32_bf16(af, bfr, accy[pt], 0, 0, 0);
    }
  }

  f32x4 accs[8];
#pragma unroll
  for (int nt = 0; nt < 8; ++nt) accs[nt] = (f32x4)0.f;
#pragma unroll
  for (int k0 = 0; k0 < 64; k0 += 32) {
    bf16x8 axr = *(const bf16x8*)&Xt[mrow][(((k0 >> 3) + quad) ^ (mrow & 7)) * 8];
    bf16x8 ax;
#pragma unroll
    for (int e = 0; e < 8; ++e)
      ax[e] = (bf16)((float)axr[e] * wls[k0 + quad * 8 + e]);
#pragma unroll
    for (int nt = 0; nt < 8; ++nt) {
      const int nrow = nt * 16 + l16;
      bf16x8 bfr = *(const bf16x8*)&Bt[nrow][(((k0 >> 3) + quad) ^ (nrow & 7)) * 8];
      accs[nt] = __builtin_amdgcn_mfma_f32_16x16x32_bf16(ax, bfr, accs[nt], 0, 0, 0);
    }
  }

#pragma unroll
  for (int pt = 0; pt < 4; ++pt) {
#pragma unroll
    for (int r = 0; r < 4; ++r) {
      const int i = wave * 16 + quad * 4 + r;
      ybuf[((size_t)(b * LL + c * CT + i)) * II + h * 64 + pt * 16 + l16] = accy[pt][r];
    }
  }
  const size_t dbase = (((size_t)(b * HH + h)) * NC + c) * (CT * NN);
#pragma unroll
  for (int nt = 0; nt < 8; ++nt) {
#pragma unroll
    for (int r = 0; r < 4; ++r) {
      const int p = wave * 16 + quad * 4 + r;
      dsb[dbase + (size_t)p * NN + nt * 16 + l16] = (bf16)accs[nt][r];
    }
  }
}

/* chain: serial over 32 chunks; in-place dS -> S_prev; final_state -> out
   512 blocks (quarter-granularity) for 2x the round-1 parallelism        */
__global__ __launch_bounds__(256) void chain_kernel(const float* __restrict__ dtda,
                                                    const float* __restrict__ A_log,
                                                    bf16* __restrict__ dsb,
                                                    float* __restrict__ fst) {
  const int blk = blockIdx.x;           /* ((b*64 + h)*4 + qtr) */
  const int b = blk >> 8, h = (blk >> 2) & 63, qtr = blk & 3;
  const int tid = threadIdx.x, wave = tid >> 6, lane = tid & 63;
  __shared__ float DcL[NC];

  const float Ah = -__expf(A_log[h]);
#pragma unroll
  for (int cc = 0; cc < 8; ++cc) {
    const int c = wave * 8 + cc;
    float2 dd = *(const float2*)(dtda + ((size_t)(b * LL + c * CT + lane) * 64 + h) * 2);
    float a = dd.x * Ah;
#pragma unroll
    for (int m = 1; m <= 32; m <<= 1) a += __shfl_xor(a, m);
    if (lane == 0) DcL[c] = __expf(a);
  }
  __syncthreads();

  const int local = qtr * 2048 + tid * 8;
  const size_t base = ((size_t)(b * HH + h)) * NC * (CT * NN) + local;
  float s[8];
#pragma unroll
  for (int e = 0; e < 8; ++e) s[e] = 0.f;

  for (int c = 0; c < NC; ++c) {
    bf16* p = dsb + base + (size_t)c * (CT * NN);
    bf16x8 d0 = *(const bf16x8*)(p);
    const float dc = DcL[c];
    bf16x8 o0;
#pragma unroll
    for (int e = 0; e < 8; ++e) o0[e] = (bf16)s[e];
    *(bf16x8*)(p) = o0;
#pragma unroll
    for (int e = 0; e < 8; ++e) s[e] = s[e] * dc + (float)d0[e];
  }
  float* fp = fst + ((size_t)(b * HH + h)) * (PP * NN) + local;
#pragma unroll
  for (int k = 0; k < 2; ++k) {
    float4 v = { s[k * 4], s[k * 4 + 1], s[k * 4 + 2], s[k * 4 + 3] };
    *(float4*)(fp + k * 4) = v;
  }
}

/* chunkB: y = Yintra + exp(cum_i)*(C·S_prev^T) + D*x */
__global__ __launch_bounds__(256) void chunkB_kernel(const bf16* __restrict__ xbc,
                                                     const float* __restrict__ dtda,
                                                     const float* __restrict__ A_log,
                                                     const float* __restrict__ Dv,
                                                     const bf16* __restrict__ spb,
                                                     float* __restrict__ ybuf) {
  const int h = blockIdx.x, c = blockIdx.y, b = blockIdx.z;
  const int g = h >> 3;
  const int tid = threadIdx.x;
  const int wave = tid >> 6, lane = tid & 63;
  const int l16 = lane & 15, quad = lane >> 4;

  __shared__ __align__(16) bf16 Cs[64][128];
  __shared__ __align__(16) bf16 Sp[64][128];
  __shared__ float es[64];

  const size_t rowbase = ((size_t)b * LL + (size_t)c * CT) * CONVD;
  {
    const int i = tid >> 2, col0 = (tid & 3) * 32;
    const bf16* gpC = xbc + rowbase + (size_t)i * CONVD + (II + GN_) + g * 128 + col0;
    const int sx = i & 15;
#pragma unroll
    for (int k = 0; k < 4; ++k) {
      const int n0 = col0 + k * 8;
      *(bf16x8*)(&Cs[i][0] + (((n0 >> 3) ^ sx) * 8)) = *(const bf16x8*)(gpC + k * 8);
    }
  }
  {
    const int p = tid >> 2, nseg = (tid & 3) * 32;
    const bf16* gp = spb + (((size_t)(b * HH + h)) * NC + c) * (CT * NN) + (size_t)p * NN + nseg;
    const int sx = p & 15;
#pragma unroll
    for (int k = 0; k < 4; ++k) {
      const int n0 = nseg + k * 8;
      bf16x8 v = *(const bf16x8*)(gp + k * 8);
      *(bf16x8*)(&Sp[p][0] + (((n0 >> 3) ^ sx) * 8)) = v;
    }
  }
  if (wave == 0) {
    const float Ah = -__expf(A_log[h]);
    float2 dd = *(const float2*)(dtda + ((size_t)(b * LL + c * CT + lane) * 64 + h) * 2);
    float s = dd.x * Ah;
#pragma unroll
    for (int d = 1; d < 64; d <<= 1) {
      float v = __shfl_up(s, d);
      if (lane >= d) s += v;
    }
    es[lane] = __expf(s);
  }
  __syncthreads();

  const int mrow = wave * 16 + l16;
  f32x4 acc[4];
#pragma unroll
  for (int pt = 0; pt < 4; ++pt) acc[pt] = (f32x4)0.f;
#pragma unroll
  for (int k0 = 0; k0 < 128; k0 += 32) {
    bf16x8 af = *(const bf16x8*)&Cs[mrow][(((k0 >> 3) + quad) ^ (mrow & 15)) * 8];
#pragma unroll
    for (int pt = 0; pt < 4; ++pt) {
      const int prow = pt * 16 + l16;
      bf16x8 bfr = *(const bf16x8*)&Sp[prow][(((k0 >> 3) + quad) ^ (prow & 15)) * 8];
      acc[pt] = __builtin_amdgcn_mfma_f32_16x16x32_bf16(af, bfr, acc[pt], 0, 0, 0);
    }
  }

  const float Dh = Dv[h];
#pragma unroll
  for (int pt = 0; pt < 4; ++pt) {
#pragma unroll
    for (int r = 0; r < 4; ++r) {
      const int i = wave * 16 + quad * 4 + r;
      const int p = pt * 16 + l16;
      const size_t row = (size_t)(b * LL + c * CT + i);
      const size_t ya = row * II + h * 64 + p;
      const float xv = (float)xbc[row * CONVD + h * 64 + p];
      ybuf[ya] = acc[pt][r] * es[i] + ybuf[ya] + Dh * xv;
    }
  }
}

/* ---------------- groupnorm(512) * silu(gate) -> bf16 ------------------- */
__global__ __launch_bounds__(256) void norm_kernel(const float* __restrict__ y,
                                                   const float* __restrict__ proj,
                                                   const float* __restrict__ nw,
                                                   bf16* __restrict__ yn) {
  const int bt = blockIdx.x, tid = threadIdx.x;
  const float* yr = y + (size_t)bt * II + tid * 16;
  float4 v[4];
  float ss = 0.f;
#pragma unroll
  for (int i = 0; i < 4; ++i) {
    v[i] = *(const float4*)(yr + i * 4);
    ss += v[i].x * v[i].x + v[i].y * v[i].y + v[i].z * v[i].z + v[i].w * v[i].w;
  }
#pragma unroll
  for (int m = 1; m <= 16; m <<= 1) ss += __shfl_xor(ss, m);
  const float rstd = rsqrtf(ss * (1.f / 512.f) + 1e-5f);

  const float* gr  = proj + (size_t)bt * NPAD + tid * 16;
  const float* nwr = nw + tid * 16;
  bf16x8 o0, o1;
#pragma unroll
  for (int i = 0; i < 4; ++i) {
    float4 gv = *(const float4*)(gr + i * 4);
    float4 nv = *(const float4*)(nwr + i * 4);
    const float* vv = (const float*)&v[i];
    const float* gg = (const float*)&gv;
    const float* nn = (const float*)&nv;
#pragma unroll
    for (int j = 0; j < 4; ++j) {
      const float gate = gg[j];
      const float val = vv[j] * rstd * nn[j] * (gate / (1.f + __expf(-gate)));
      if (i < 2) o0[i * 4 + j] = (bf16)val;
      else       o1[(i - 2) * 4 + j] = (bf16)val;
    }
  }
  bf16* dst = yn + (size_t)bt * II + tid * 16;
  *(bf16x8*)(dst)     = o0;
  *(bf16x8*)(dst + 8) = o1;
}

extern "C" void kernel_launch(void* const* d_in, const int* in_sizes, int n_in,
                              void* d_out, int out_size, void* d_ws, size_t ws_size,
                              hipStream_t stream) {
  const float* hs      = (const float*)d_in[0];
  const float* w_in    = (const float*)d_in[1];
  const float* cw      = (const float*)d_in[2];
  const float* cb      = (const float*)d_in[3];
  const float* dt_bias = (const float*)d_in[4];
  const float* A_log   = (const float*)d_in[5];
  const float* Dv      = (const float*)d_in[6];
  const float* nw      = (const float*)d_in[7];
  const float* w_out   = (const float*)d_in[8];

  char* ws = (char*)d_ws;
  bf16*  hsb   = (bf16*)(ws + WS_HSB);
  bf16*  winb  = (bf16*)(ws + WS_WINB);
  bf16*  dsb   = (bf16*)(ws + WS_DSB);
  float* proj  = (float*)(ws + WS_PROJ);
  bf16*  xbc   = (bf16*)(ws + WS_XBC);
  float* dtda  = (float*)(ws + WS_DTDA);
  float* ybuf  = (float*)(ws + WS_Y);
  bf16*  ynb   = (bf16*)(ws + WS_YNB);
  bf16*  woutb = (bf16*)(ws + WS_WOUTB);

  float* outp = (float*)d_out;

  cast_kernel<<<16384, 256, 0, stream>>>(hs, hsb, 16777216L, 16777216L);
  cast_kernel<<<41984, 256, 0, stream>>>(w_in, winb, (long)PROJD * DM, (long)NPAD * DM);

  gemm256<<<(BT / 256) * (NPAD / 256), 512, 0, stream>>>(hsb, winb, proj, BT, NPAD, DM, NPAD / 256);

  conv_kernel<<<dim3(CONVD / 256, BT / CTILE), 256, 0, stream>>>(proj, cw, cb, xbc);
  dt_kernel<<<(BT * HH) / 256, 256, 0, stream>>>(proj, dt_bias, A_log, dtda);
  convstate_kernel<<<(BB * CONVD * 3 + 255) / 256, 256, 0, stream>>>(proj, outp + OUT_OFS_CONV);

  chunkA_kernel<<<dim3(HH, NC, BB), 256, 0, stream>>>(xbc, dtda, A_log, ybuf, dsb);
  chain_kernel<<<BB * HH * 4, 256, 0, stream>>>(dtda, A_log, dsb, outp + OUT_OFS_STATE);
  chunkB_kernel<<<dim3(HH, NC, BB), 256, 0, stream>>>(xbc, dtda, A_log, Dv, dsb, ybuf);

  /* w_out cast deferred here so woutb/ynb can overlay the dead hsb/winb/dsb region */
  cast_kernel<<<16384, 256, 0, stream>>>(w_out, woutb, 16777216L, 16777216L);
  norm_kernel<<<BT, 256, 0, stream>>>(ybuf, proj, nw, ynb);

  gemm256<<<(BT / 256) * (DM / 256), 512, 0, stream>>>(ynb, woutb, outp, BT, DM, II, DM / 256);
}

// Round 3
// 962.176 us; speedup vs baseline: 1.4720x; 1.0125x over previous
//
#include <hip/hip_runtime.h>
#include <cstdint>
#include <cstddef>

typedef __bf16 bf16;
typedef float f32x4 __attribute__((ext_vector_type(4)));
typedef bf16 bf16x8 __attribute__((ext_vector_type(8)));
typedef bf16 bf16x4 __attribute__((ext_vector_type(4)));

#define DM    4096
#define LL    2048
#define BB    2
#define BT    4096      /* B*L */
#define II    4096
#define GN_   1024
#define CONVD 6144
#define PROJD 10304
#define NPAD  10496     /* padded to multiple of 256 for the 256^2 GEMM */
#define HH    64
#define PP    64
#define NN    128
#define CT    64        /* chunk length */
#define NC    32        /* chunks per sequence */

/* ---- output layout (floats) ---- */
#define OUT_OFS_CONV  16777216
#define OUT_OFS_STATE 16814080

/* ---- workspace layout (bytes) ---- */
#define WS_HSB    0UL                   /* bf16 4096x4096      33554432 */
#define WS_WINB   33554432UL            /* bf16 10496x4096     85983232 */
#define WS_DSB    0UL                   /* bf16 [b][h][c][64][128] 67108864 */
#define WS_PROJ   119537664UL           /* f32  4096x10496    171966464 */
#define WS_XBC    291504128UL           /* bf16 4096x6144      50331648 */
#define WS_DTDA   392167424UL           /* f32  4096x64x2       2097152 */
#define WS_Y      394264576UL           /* f32  4096x4096      67108864 */
#define WS_WOUTB  0UL                   /* bf16 4096x4096 (after chunkB) */
#define WS_YNB    33554432UL            /* bf16 4096x4096 (after chunkB) */

__device__ __forceinline__ void gl2lds16(const void* g, void* l) {
  __builtin_amdgcn_global_load_lds(
      (__attribute__((address_space(1))) unsigned int*)(uintptr_t)g,
      (__attribute__((address_space(3))) unsigned int*)(uintptr_t)l, 16, 0, 0);
}

/* ------------- merged cast fp32 -> bf16: hs (copy) + w_in (pad) --------- */
__global__ __launch_bounds__(256) void cast2_kernel(const float* __restrict__ s1,
                                                    bf16* __restrict__ d1,
                                                    const float* __restrict__ s2,
                                                    bf16* __restrict__ d2,
                                                    long nsrc2, long ndst2) {
  if (blockIdx.x < 16384) {
    long i = ((long)blockIdx.x * 256 + threadIdx.x) * 4;
    float4 v = *(const float4*)(s1 + i);
    bf16x4 o;
    o[0] = (bf16)v.x; o[1] = (bf16)v.y; o[2] = (bf16)v.z; o[3] = (bf16)v.w;
    *(bf16x4*)(d1 + i) = o;
  } else {
    long i = ((long)(blockIdx.x - 16384) * 256 + threadIdx.x) * 4;
    if (i >= ndst2) return;
    bf16x4 o;
    if (i < nsrc2) {
      float4 v = *(const float4*)(s2 + i);
      o[0] = (bf16)v.x; o[1] = (bf16)v.y; o[2] = (bf16)v.z; o[3] = (bf16)v.w;
    } else {
      o[0] = (bf16)0.f; o[1] = (bf16)0.f; o[2] = (bf16)0.f; o[3] = (bf16)0.f;
    }
    *(bf16x4*)(d2 + i) = o;
  }
}

/* ---------------- cast fp32 -> bf16 (plain) ----------------------------- */
__global__ __launch_bounds__(256) void cast_kernel(const float* __restrict__ src,
                                                   bf16* __restrict__ dst,
                                                   long nsrc, long ndst) {
  long i = ((long)blockIdx.x * 256 + threadIdx.x) * 4;
  if (i >= ndst) return;
  bf16x4 o;
  if (i < nsrc) {
    float4 v = *(const float4*)(src + i);
    o[0] = (bf16)v.x; o[1] = (bf16)v.y; o[2] = (bf16)v.z; o[3] = (bf16)v.w;
  } else {
    o[0] = (bf16)0.f; o[1] = (bf16)0.f; o[2] = (bf16)0.f; o[3] = (bf16)0.f;
  }
  *(bf16x4*)(dst + i) = o;
}

/* =====================================================================
   256x256 8-phase bf16 GEMM, C[M,N] = A[M,K] * B[N,K]^T  (C fp32)
   ===================================================================== */
#define BARF() do { asm volatile("" ::: "memory");                    \
                    __builtin_amdgcn_s_barrier();                     \
                    asm volatile("" ::: "memory"); } while (0)
#define WAITLGKM0() do { asm volatile("s_waitcnt lgkmcnt(0)" ::: "memory"); \
                         __builtin_amdgcn_sched_barrier(0); } while (0)
#define HINTLGKM8() asm volatile("s_waitcnt lgkmcnt(8)" ::: "memory")
#define WAITVM(n) asm volatile("s_waitcnt vmcnt(" #n ")" ::: "memory")
#define PRIO1 __builtin_amdgcn_s_setprio(1)
#define PRIO0 __builtin_amdgcn_s_setprio(0)

__device__ __forceinline__ void stage_A_half(const bf16* __restrict__ A, int K,
                                             int arow, int kt, bf16* lds,
                                             int h, int tid) {
#pragma unroll
  for (int j = 0; j < 2; ++j) {
    const int r  = h * 64 + j * 128 + (tid >> 3);
    const int cb = (tid & 7) * 16;
    const int cs = cb ^ ((r & 7) << 4);
    gl2lds16(A + (size_t)(arow + r) * K + kt * 64 + (cs >> 1),
             lds + r * 64 + (cb >> 1));
  }
}
__device__ __forceinline__ void stage_B_half(const bf16* __restrict__ B, int K,
                                             int brow, int kt, bf16* lds,
                                             int h, int tid) {
#pragma unroll
  for (int j = 0; j < 2; ++j) {
    const int quarter = j * 2 + (tid >> 8);
    const int kq = tid & 255;
    const int r  = quarter * 64 + h * 32 + (kq >> 3);
    const int cb = (kq & 7) * 16;
    const int cs = cb ^ ((r & 7) << 4);
    gl2lds16(B + (size_t)(brow + r) * K + kt * 64 + (cs >> 1),
             lds + r * 64 + (cb >> 1));
  }
}

#define LDA4(p, mh) do {                                                     \
  _Pragma("unroll") for (int mt = 0; mt < 4; ++mt)                           \
  _Pragma("unroll") for (int kk = 0; kk < 2; ++kk) {                         \
    const int rr = wm * 128 + (mh) * 64 + mt * 16 + l16;                     \
    const int cc = (kk * 64 + quad * 16) ^ ((rr & 7) << 4);                  \
    a_[mt][kk] = *(const bf16x8*)((const char*)(&sA[p][rr][0]) + cc);        \
  } } while (0)

#define LDB2(p, np, barr) do {                                               \
  _Pragma("unroll") for (int nt = 0; nt < 2; ++nt)                           \
  _Pragma("unroll") for (int kk = 0; kk < 2; ++kk) {                         \
    const int rr = wn * 64 + (np) * 32 + nt * 16 + l16;                      \
    const int cc = (kk * 64 + quad * 16) ^ ((rr & 7) << 4);                  \
    barr[nt][kk] = *(const bf16x8*)((const char*)(&sB[p][rr][0]) + cc);      \
  } } while (0)

#define MFMAQ(mh, barr, nb0) do {                                            \
  _Pragma("unroll") for (int kk = 0; kk < 2; ++kk)                           \
  _Pragma("unroll") for (int mt = 0; mt < 4; ++mt)                           \
  _Pragma("unroll") for (int nt = 0; nt < 2; ++nt)                           \
    acc[(mh) * 4 + mt][(nb0) + nt] = __builtin_amdgcn_mfma_f32_16x16x32_bf16(\
        a_[mt][kk], barr[nt][kk], acc[(mh) * 4 + mt][(nb0) + nt], 0, 0, 0);  \
  } while (0)

__global__ __launch_bounds__(512, 2) void gemm256(const bf16* __restrict__ A,
                                                  const bf16* __restrict__ B,
                                                  float* __restrict__ C,
                                                  int M, int N, int K, int NB) {
  __shared__ __align__(16) bf16 sA[2][256][64];
  __shared__ __align__(16) bf16 sB[2][256][64];

  const int tid  = threadIdx.x;
  const int wave = tid >> 6, lane = tid & 63;
  const int l16  = lane & 15, quad = lane >> 4;
  const int wm   = wave >> 2, wn = wave & 3;

  const int nwg = gridDim.x;
  const int q = nwg >> 3, r8 = nwg & 7;
  const int xcd = blockIdx.x & 7, idx = blockIdx.x >> 3;
  const int wgid = (xcd < r8 ? xcd * (q + 1) : r8 * (q + 1) + (xcd - r8) * q) + idx;
  const int mb = wgid / NB, nb = wgid - mb * NB;
  const int arow = mb * 256, brow = nb * 256;

  f32x4 acc[8][4];
#pragma unroll
  for (int i = 0; i < 8; ++i)
#pragma unroll
    for (int j = 0; j < 4; ++j) acc[i][j] = (f32x4)0.f;

  const int NT = K >> 6;

  stage_A_half(A, K, arow, 0, &sA[0][0][0], 0, tid);
  stage_B_half(B, K, brow, 0, &sB[0][0][0], 0, tid);
  stage_A_half(A, K, arow, 0, &sA[0][0][0], 1, tid);
  stage_B_half(B, K, brow, 0, &sB[0][0][0], 1, tid);
  stage_A_half(A, K, arow, 1, &sA[1][0][0], 0, tid);
  stage_B_half(B, K, brow, 1, &sB[1][0][0], 0, tid);
  stage_A_half(A, K, arow, 1, &sA[1][0][0], 1, tid);
  WAITVM(6);
  BARF();

  bf16x8 a_[4][2], b0_[2][2], b1_[2][2];

  for (int i = 0; i < NT / 2; ++i) {
    const int t1o = 2 * i + 1;
    const int t2  = (2 * i + 2 < NT) ? 2 * i + 2 : NT - 1;
    const int t3  = (2 * i + 3 < NT) ? 2 * i + 3 : NT - 1;

    LDA4(0, 0); LDB2(0, 0, b0_);
    stage_B_half(B, K, brow, t1o, &sB[1][0][0], 1, tid);
    HINTLGKM8();
    BARF(); WAITLGKM0();
    PRIO1; MFMAQ(0, b0_, 0); PRIO0;
    BARF();
    LDB2(0, 1, b1_);
    stage_A_half(A, K, arow, t2, &sA[0][0][0], 0, tid);
    BARF(); WAITLGKM0();
    PRIO1; MFMAQ(0, b1_, 2); PRIO0;
    BARF();
    LDA4(0, 1);
    stage_B_half(B, K, brow, t2, &sB[0][0][0], 0, tid);
    BARF(); WAITLGKM0();
    PRIO1; MFMAQ(1, b1_, 2); PRIO0;
    BARF();
    stage_A_half(A, K, arow, t2, &sA[0][0][0], 1, tid);
    WAITVM(6);
    BARF();
    PRIO1; MFMAQ(1, b0_, 0); PRIO0;
    BARF();
    LDA4(1, 0); LDB2(1, 0, b0_);
    stage_B_half(B, K, brow, t2, &sB[0][0][0], 1, tid);
    HINTLGKM8();
    BARF(); WAITLGKM0();
    PRIO1; MFMAQ(0, b0_, 0); PRIO0;
    BARF();
    LDB2(1, 1, b1_);
    stage_A_half(A, K, arow, t3, &sA[1][0][0], 0, tid);
    BARF(); WAITLGKM0();
    PRIO1; MFMAQ(0, b1_, 2); PRIO0;
    BARF();
    LDA4(1, 1);
    stage_B_half(B, K, brow, t3, &sB[1][0][0], 0, tid);
    BARF(); WAITLGKM0();
    PRIO1; MFMAQ(1, b1_, 2); PRIO0;
    BARF();
    stage_A_half(A, K, arow, t3, &sA[1][0][0], 1, tid);
    WAITVM(6);
    BARF();
    PRIO1; MFMAQ(1, b0_, 0); PRIO0;
    BARF();
  }
  asm volatile("s_waitcnt vmcnt(0)" ::: "memory");
  __builtin_amdgcn_s_barrier();

#pragma unroll
  for (int mt = 0; mt < 8; ++mt) {
    const int row0 = arow + wm * 128 + mt * 16 + quad * 4;
#pragma unroll
    for (int nt = 0; nt < 4; ++nt) {
      const int col = brow + wn * 64 + nt * 16 + l16;
#pragma unroll
      for (int r = 0; r < 4; ++r)
        C[(size_t)(row0 + r) * N + col] = acc[mt][nt][r];
    }
  }
}

/* ---------------- conv(K=4) + SiLU, rolling-window, bf16 out ------------ */
#define CTILE 64
__global__ __launch_bounds__(256) void conv_kernel(const float* __restrict__ proj,
                                                   const float* __restrict__ cw,
                                                   const float* __restrict__ cb,
                                                   bf16* __restrict__ xbc) {
  const int c   = blockIdx.x * 256 + threadIdx.x;
  const int bt0 = blockIdx.y * CTILE;
  const int t0  = bt0 & (LL - 1);
  const float4 w = *(const float4*)(cw + c * 4);
  const float bias = cb[c];
  const float* p = proj + (size_t)bt0 * NPAD + II + c;
  float h0, h1, h2;
  if (t0 == 0) {
    h0 = 0.f; h1 = 0.f; h2 = 0.f;
  } else {
    h0 = p[-3 * (ptrdiff_t)NPAD];
    h1 = p[-2 * (ptrdiff_t)NPAD];
    h2 = p[-(ptrdiff_t)NPAD];
  }
  bf16* q = xbc + (size_t)bt0 * CONVD + c;
#pragma unroll 8
  for (int t = 0; t < CTILE; ++t) {
    const float cur = p[(ptrdiff_t)t * NPAD];
    const float acc = bias + h0 * w.x + h1 * w.y + h2 * w.z + cur * w.w;
    q[(size_t)t * CONVD] = (bf16)(acc / (1.f + __expf(-acc)));
    h0 = h1; h1 = h2; h2 = cur;
  }
}

/* -------- merged: dtda + conv_state transpose --------------------------- */
__global__ __launch_bounds__(256) void dtcs_kernel(const float* __restrict__ proj,
                                                   const float* __restrict__ dt_bias,
                                                   const float* __restrict__ A_log,
                                                   float* __restrict__ dtda,
                                                   float* __restrict__ outp) {
  const int bid = blockIdx.x;
  if (bid < 1024) {
    const int idx = bid * 256 + threadIdx.x;
    const int bt = idx >> 6, h = idx & 63;
    const float z = proj[(size_t)bt * NPAD + (II + CONVD) + h] + dt_bias[h];
    const float sp = (z > 20.f) ? z : log1pf(__expf(z));
    const float a = -__expf(A_log[h]);
    float2 o; o.x = sp; o.y = __expf(sp * a);
    *(float2*)(dtda + (size_t)idx * 2) = o;
  } else {
    const int idx = (bid - 1024) * 256 + threadIdx.x;
    if (idx >= BB * CONVD * 3) return;
    const int b = idx / (CONVD * 3);
    const int r = idx - b * CONVD * 3;
    const int c = r / 3, j = r - c * 3;
    outp[idx] = proj[((size_t)b * LL + (LL - 3 + j)) * NPAD + II + c];
  }
}

/* =============== chunked SSD scan =============== */
/* grid remap (1-D, 4096): hh in bits [5:3] so the 8 heads of a group
   (sharing one B/C slice) land on the SAME XCD (dlin = 8 -> same L2). */
#define SCAN_DECODE()                                                  \
  const int lin = blockIdx.x;                                          \
  const int hh  = (lin >> 3) & 7;                                      \
  const int id  = (lin & 7) | ((lin >> 6) << 3);                       \
  const int g   = id >> 6, c = (id >> 1) & 31, b = id & 1;             \
  const int h   = g * 8 + hh;

/* chunkA: per (b,h,c): G=C·B^T, W=mask(G), Yintra=W·X, dS=(wX)^T·B        */
__global__ __launch_bounds__(256) void chunkA_kernel(const bf16* __restrict__ xbc,
                                                     const float* __restrict__ dtda,
                                                     const float* __restrict__ A_log,
                                                     float* __restrict__ ybuf,
                                                     bf16* __restrict__ dsb) {
  SCAN_DECODE();
  const int tid = threadIdx.x;
  const int wave = tid >> 6, lane = tid & 63;
  const int l16 = lane & 15, quad = lane >> 4;

  __shared__ __align__(16) bf16 CsBt[8192];
  __shared__ __align__(16) bf16 Bs[64][128];
  __shared__ __align__(16) bf16 Xt[64][64];
  __shared__ __align__(16) bf16 Ws[64][64];
  __shared__ float cums[64], dtps[64], wls[64];

  bf16 (*Cs)[128] = (bf16(*)[128])CsBt;
  bf16 (*Bt)[64]  = (bf16(*)[64])CsBt;

  const size_t rowbase = ((size_t)b * LL + (size_t)c * CT) * CONVD;

  /* Cs/Bs staging via global_load_lds: linear LDS dest (wave base + lane*16B
     = 4 rows/instr), per-lane pre-swizzled global source (chunk ^ row&15) */
  {
    const int r0 = wave * 16;
    const bf16* gC = xbc + rowbase + (II + GN_) + g * 128;
    const bf16* gB = xbc + rowbase + II + g * 128;
#pragma unroll
    for (int j = 0; j < 4; ++j) {
      const int r  = r0 + j * 4 + (lane >> 4);
      const int ch = (lane & 15) ^ (r & 15);
      gl2lds16(gC + (size_t)r * CONVD + ch * 8, &Cs[r0 + j * 4][0]);
      gl2lds16(gB + (size_t)r * CONVD + ch * 8, &Bs[r0 + j * 4][0]);
    }
  }
  {
    const int j = tid >> 2, p0 = (tid & 3) * 16;
    const bf16* gpX = xbc + rowbase + (size_t)j * CONVD + h * 64 + p0;
#pragma unroll
    for (int k = 0; k < 2; ++k) {
      bf16x8 v = *(const bf16x8*)(gpX + k * 8);
#pragma unroll
      for (int e = 0; e < 8; ++e) {
        const int pp = p0 + k * 8 + e;
        Xt[pp][(((j >> 3) ^ (pp & 7)) * 8) + (j & 7)] = v[e];
      }
    }
  }
  if (wave == 0) {
    const float Ah = -__expf(A_log[h]);
    float2 dd = *(const float2*)(dtda + ((size_t)((b * LL + c * CT + lane)) * 64 + h) * 2);
    float s = dd.x * Ah;
#pragma unroll
    for (int d = 1; d < 64; d <<= 1) {
      float v = __shfl_up(s, d);
      if (lane >= d) s += v;
    }
    const float tot = __shfl(s, 63);
    cums[lane] = s;
    dtps[lane] = dd.x;
    wls[lane]  = __expf(tot - s) * dd.x;
  }
  __syncthreads();

  const int mrow = wave * 16 + l16;
  {
    f32x4 accg[4];
#pragma unroll
    for (int nt = 0; nt < 4; ++nt) accg[nt] = (f32x4)0.f;
#pragma unroll
    for (int k0 = 0; k0 < 128; k0 += 32) {
      bf16x8 af = *(const bf16x8*)&Cs[mrow][(((k0 >> 3) + quad) ^ (mrow & 15)) * 8];
#pragma unroll
      for (int nt = 0; nt < 4; ++nt) {
        const int nrow = nt * 16 + l16;
        bf16x8 bfr = *(const bf16x8*)&Bs[nrow][(((k0 >> 3) + quad) ^ (nrow & 15)) * 8];
        accg[nt] = __builtin_amdgcn_mfma_f32_16x16x32_bf16(af, bfr, accg[nt], 0, 0, 0);
      }
    }
#pragma unroll
    for (int nt = 0; nt < 4; ++nt) {
      const int j = nt * 16 + l16;
#pragma unroll
      for (int r = 0; r < 4; ++r) {
        const int i = wave * 16 + quad * 4 + r;
        float v = 0.f;
        if (j <= i) v = accg[nt][r] * __expf(cums[i] - cums[j]) * dtps[j];
        Ws[i][(((j >> 3) ^ (i & 7)) * 8) + (j & 7)] = (bf16)v;
      }
    }
  }
  __syncthreads();

  {
    const int n = tid >> 1, j0 = (tid & 1) * 32;
#pragma unroll
    for (int k = 0; k < 4; ++k) {
      bf16x8 v;
#pragma unroll
      for (int e = 0; e < 8; ++e) {
        const int j = j0 + k * 8 + e;
        v[e] = Bs[j][(((n >> 3) ^ (j & 15)) * 8) + (n & 7)];
      }
      *(bf16x8*)(&Bt[n][((((j0 + k * 8) >> 3) ^ (n & 7)) * 8)]) = v;
    }
  }
  __syncthreads();

  f32x4 accy[4];
#pragma unroll
  for (int pt = 0; pt < 4; ++pt) accy[pt] = (f32x4)0.f;
#pragma unroll
  for (int k0 = 0; k0 < 64; k0 += 32) {
    bf16x8 af = *(const bf16x8*)&Ws[mrow][(((k0 >> 3) + quad) ^ (mrow & 7)) * 8];
#pragma unroll
    for (int pt = 0; pt < 4; ++pt) {
      const int prow = pt * 16 + l16;
      bf16x8 bfr = *(const bf16x8*)&Xt[prow][(((k0 >> 3) + quad) ^ (prow & 7)) * 8];
      accy[pt] = __builtin_amdgcn_mfma_f32_16x16x32_bf16(af, bfr, accy[pt], 0, 0, 0);
    }
  }

  f32x4 accs[8];
#pragma unroll
  for (int nt = 0; nt < 8; ++nt) accs[nt] = (f32x4)0.f;
#pragma unroll
  for (int k0 = 0; k0 < 64; k0 += 32) {
    bf16x8 axr = *(const bf16x8*)&Xt[mrow][(((k0 >> 3) + quad) ^ (mrow & 7)) * 8];
    bf16x8 ax;
#pragma unroll
    for (int e = 0; e < 8; ++e)
      ax[e] = (bf16)((float)axr[e] * wls[k0 + quad * 8 + e]);
#pragma unroll
    for (int nt = 0; nt < 8; ++nt) {
      const int nrow = nt * 16 + l16;
      bf16x8 bfr = *(const bf16x8*)&Bt[nrow][(((k0 >> 3) + quad) ^ (nrow & 7)) * 8];
      accs[nt] = __builtin_amdgcn_mfma_f32_16x16x32_bf16(ax, bfr, accs[nt], 0, 0, 0);
    }
  }

#pragma unroll
  for (int pt = 0; pt < 4; ++pt) {
#pragma unroll
    for (int r = 0; r < 4; ++r) {
      const int i = wave * 16 + quad * 4 + r;
      ybuf[((size_t)(b * LL + c * CT + i)) * II + h * 64 + pt * 16 + l16] = accy[pt][r];
    }
  }
  const size_t dbase = (((size_t)(b * HH + h)) * NC + c) * (CT * NN);
#pragma unroll
  for (int nt = 0; nt < 8; ++nt) {
#pragma unroll
    for (int r = 0; r < 4; ++r) {
      const int p = wave * 16 + quad * 4 + r;
      dsb[dbase + (size_t)p * NN + nt * 16 + l16] = (bf16)accs[nt][r];
    }
  }
}

/* chain: serial over 32 chunks; in-place dS -> S_prev; final_state -> out */
__global__ __launch_bounds__(256) void chain_kernel(const float* __restrict__ dtda,
                                                    const float* __restrict__ A_log,
                                                    bf16* __restrict__ dsb,
                                                    float* __restrict__ fst) {
  const int blk = blockIdx.x;           /* ((b*64 + h)*4 + qtr) */
  const int b = blk >> 8, h = (blk >> 2) & 63, qtr = blk & 3;
  const int tid = threadIdx.x, wave = tid >> 6, lane = tid & 63;
  __shared__ float DcL[NC];

  const float Ah = -__expf(A_log[h]);
#pragma unroll
  for (int cc = 0; cc < 8; ++cc) {
    const int c = wave * 8 + cc;
    float2 dd = *(const float2*)(dtda + ((size_t)(b * LL + c * CT + lane) * 64 + h) * 2);
    float a = dd.x * Ah;
#pragma unroll
    for (int m = 1; m <= 32; m <<= 1) a += __shfl_xor(a, m);
    if (lane == 0) DcL[c] = __expf(a);
  }

  const int local = qtr * 2048 + tid * 8;
  const size_t base = ((size_t)(b * HH + h)) * NC * (CT * NN) + local;
  float s[8];
#pragma unroll
  for (int e = 0; e < 8; ++e) s[e] = 0.f;

  /* prefetch chunk 0 before the barrier */
  bf16x8 d0 = *(const bf16x8*)(dsb + base);
  __syncthreads();

  for (int c = 0; c < NC; ++c) {
    bf16* p = dsb + base + (size_t)c * (CT * NN);
    bf16x8 dn;
    if (c + 1 < NC) dn = *(const bf16x8*)(p + (CT * NN));   /* prefetch next */
    const float dc = DcL[c];
    bf16x8 o0;
#pragma unroll
    for (int e = 0; e < 8; ++e) o0[e] = (bf16)s[e];
    *(bf16x8*)(p) = o0;
#pragma unroll
    for (int e = 0; e < 8; ++e) s[e] = s[e] * dc + (float)d0[e];
    d0 = dn;
  }
  float* fp = fst + ((size_t)(b * HH + h)) * (PP * NN) + local;
#pragma unroll
  for (int k = 0; k < 2; ++k) {
    float4 v = { s[k * 4], s[k * 4 + 1], s[k * 4 + 2], s[k * 4 + 3] };
    *(float4*)(fp + k * 4) = v;
  }
}

/* chunkB: y = Yintra + exp(cum_i)*(C·S_prev^T) + D*x */
__global__ __launch_bounds__(256) void chunkB_kernel(const bf16* __restrict__ xbc,
                                                     const float* __restrict__ dtda,
                                                     const float* __restrict__ A_log,
                                                     const float* __restrict__ Dv,
                                                     const bf16* __restrict__ spb,
                                                     float* __restrict__ ybuf) {
  SCAN_DECODE();
  const int tid = threadIdx.x;
  const int wave = tid >> 6, lane = tid & 63;
  const int l16 = lane & 15, quad = lane >> 4;

  __shared__ __align__(16) bf16 Cs[64][128];
  __shared__ __align__(16) bf16 Sp[64][128];
  __shared__ float es[64];

  const size_t rowbase = ((size_t)b * LL + (size_t)c * CT) * CONVD;
  {
    const int r0 = wave * 16;
    const bf16* gC = xbc + rowbase + (II + GN_) + g * 128;
    const bf16* gS = spb + (((size_t)(b * HH + h)) * NC + c) * (CT * NN);
#pragma unroll
    for (int j = 0; j < 4; ++j) {
      const int r  = r0 + j * 4 + (lane >> 4);
      const int ch = (lane & 15) ^ (r & 15);
      gl2lds16(gC + (size_t)r * CONVD + ch * 8, &Cs[r0 + j * 4][0]);
      gl2lds16(gS + (size_t)r * NN   + ch * 8, &Sp[r0 + j * 4][0]);
    }
  }
  if (wave == 0) {
    const float Ah = -__expf(A_log[h]);
    float2 dd = *(const float2*)(dtda + ((size_t)(b * LL + c * CT + lane) * 64 + h) * 2);
    float s = dd.x * Ah;
#pragma unroll
    for (int d = 1; d < 64; d <<= 1) {
      float v = __shfl_up(s, d);
      if (lane >= d) s += v;
    }
    es[lane] = __expf(s);
  }
  __syncthreads();

  const int mrow = wave * 16 + l16;
  f32x4 acc[4];
#pragma unroll
  for (int pt = 0; pt < 4; ++pt) acc[pt] = (f32x4)0.f;
#pragma unroll
  for (int k0 = 0; k0 < 128; k0 += 32) {
    bf16x8 af = *(const bf16x8*)&Cs[mrow][(((k0 >> 3) + quad) ^ (mrow & 15)) * 8];
#pragma unroll
    for (int pt = 0; pt < 4; ++pt) {
      const int prow = pt * 16 + l16;
      bf16x8 bfr = *(const bf16x8*)&Sp[prow][(((k0 >> 3) + quad) ^ (prow & 15)) * 8];
      acc[pt] = __builtin_amdgcn_mfma_f32_16x16x32_bf16(af, bfr, acc[pt], 0, 0, 0);
    }
  }

  const float Dh = Dv[h];
#pragma unroll
  for (int pt = 0; pt < 4; ++pt) {
#pragma unroll
    for (int r = 0; r < 4; ++r) {
      const int i = wave * 16 + quad * 4 + r;
      const int p = pt * 16 + l16;
      const size_t row = (size_t)(b * LL + c * CT + i);
      const size_t ya = row * II + h * 64 + p;
      const float xv = (float)xbc[row * CONVD + h * 64 + p];
      ybuf[ya] = acc[pt][r] * es[i] + ybuf[ya] + Dh * xv;
    }
  }
}

/* ---------------- groupnorm(512) * silu(gate) -> bf16 ------------------- */
__global__ __launch_bounds__(256) void norm_kernel(const float* __restrict__ y,
                                                   const float* __restrict__ proj,
                                                   const float* __restrict__ nw,
                                                   bf16* __restrict__ yn) {
  const int bt = blockIdx.x, tid = threadIdx.x;
  const float* yr = y + (size_t)bt * II + tid * 16;
  float4 v[4];
  float ss = 0.f;
#pragma unroll
  for (int i = 0; i < 4; ++i) {
    v[i] = *(const float4*)(yr + i * 4);
    ss += v[i].x * v[i].x + v[i].y * v[i].y + v[i].z * v[i].z + v[i].w * v[i].w;
  }
#pragma unroll
  for (int m = 1; m <= 16; m <<= 1) ss += __shfl_xor(ss, m);
  const float rstd = rsqrtf(ss * (1.f / 512.f) + 1e-5f);

  const float* gr  = proj + (size_t)bt * NPAD + tid * 16;
  const float* nwr = nw + tid * 16;
  bf16x8 o0, o1;
#pragma unroll
  for (int i = 0; i < 4; ++i) {
    float4 gv = *(const float4*)(gr + i * 4);
    float4 nv = *(const float4*)(nwr + i * 4);
    const float* vv = (const float*)&v[i];
    const float* gg = (const float*)&gv;
    const float* nn = (const float*)&nv;
#pragma unroll
    for (int j = 0; j < 4; ++j) {
      const float gate = gg[j];
      const float val = vv[j] * rstd * nn[j] * (gate / (1.f + __expf(-gate)));
      if (i < 2) o0[i * 4 + j] = (bf16)val;
      else       o1[(i - 2) * 4 + j] = (bf16)val;
    }
  }
  bf16* dst = yn + (size_t)bt * II + tid * 16;
  *(bf16x8*)(dst)     = o0;
  *(bf16x8*)(dst + 8) = o1;
}

extern "C" void kernel_launch(void* const* d_in, const int* in_sizes, int n_in,
                              void* d_out, int out_size, void* d_ws, size_t ws_size,
                              hipStream_t stream) {
  const float* hs      = (const float*)d_in[0];
  const float* w_in    = (const float*)d_in[1];
  const float* cw      = (const float*)d_in[2];
  const float* cb      = (const float*)d_in[3];
  const float* dt_bias = (const float*)d_in[4];
  const float* A_log   = (const float*)d_in[5];
  const float* Dv      = (const float*)d_in[6];
  const float* nw      = (const float*)d_in[7];
  const float* w_out   = (const float*)d_in[8];

  char* ws = (char*)d_ws;
  bf16*  hsb   = (bf16*)(ws + WS_HSB);
  bf16*  winb  = (bf16*)(ws + WS_WINB);
  bf16*  dsb   = (bf16*)(ws + WS_DSB);
  float* proj  = (float*)(ws + WS_PROJ);
  bf16*  xbc   = (bf16*)(ws + WS_XBC);
  float* dtda  = (float*)(ws + WS_DTDA);
  float* ybuf  = (float*)(ws + WS_Y);
  bf16*  ynb   = (bf16*)(ws + WS_YNB);
  bf16*  woutb = (bf16*)(ws + WS_WOUTB);

  float* outp = (float*)d_out;

  cast2_kernel<<<58368, 256, 0, stream>>>(hs, hsb, w_in, winb,
                                          (long)PROJD * DM, (long)NPAD * DM);

  gemm256<<<(BT / 256) * (NPAD / 256), 512, 0, stream>>>(hsb, winb, proj, BT, NPAD, DM, NPAD / 256);

  conv_kernel<<<dim3(CONVD / 256, BT / CTILE), 256, 0, stream>>>(proj, cw, cb, xbc);
  dtcs_kernel<<<1168, 256, 0, stream>>>(proj, dt_bias, A_log, dtda, outp + OUT_OFS_CONV);

  chunkA_kernel<<<4096, 256, 0, stream>>>(xbc, dtda, A_log, ybuf, dsb);
  chain_kernel<<<BB * HH * 4, 256, 0, stream>>>(dtda, A_log, dsb, outp + OUT_OFS_STATE);
  chunkB_kernel<<<4096, 256, 0, stream>>>(xbc, dtda, A_log, Dv, dsb, ybuf);

  cast_kernel<<<16384, 256, 0, stream>>>(w_out, woutb, 16777216L, 16777216L);
  norm_kernel<<<BT, 256, 0, stream>>>(ybuf, proj, nw, ynb);

  gemm256<<<(BT / 256) * (DM / 256), 512, 0, stream>>>(ynb, woutb, outp, BT, DM, II, DM / 256);
}

// Round 4
// 906.355 us; speedup vs baseline: 1.5627x; 1.0616x over previous
//
#include <hip/hip_runtime.h>
#include <cstdint>
#include <cstddef>

typedef __bf16 bf16;
typedef float f32x4 __attribute__((ext_vector_type(4)));
typedef bf16 bf16x8 __attribute__((ext_vector_type(8)));
typedef bf16 bf16x4 __attribute__((ext_vector_type(4)));

#define DM    4096
#define LL    2048
#define BB    2
#define BT    4096      /* B*L */
#define II    4096
#define GN_   1024
#define CONVD 6144
#define PROJD 10304
#define NPAD  10496     /* padded to multiple of 256 for the 256^2 GEMM */
#define HH    64
#define PP    64
#define NN    128
#define CT    64        /* chunk length */
#define NC    32        /* chunks per sequence */

/* ---- output layout (floats) ---- */
#define OUT_OFS_CONV  16777216
#define OUT_OFS_STATE 16814080

/* ---- workspace layout (bytes) ----
   phase 1 (gemm1):  hsb[0,33.5M) winb[33.5M,119.5M)
   phase 2 (scan):   dsb[0,67.1M) overlays dead hsb+winb
   phase 3 (out):    ynb[67.1M,100.7M) overlays dead upper winb
   always live:      proj(bf16), xbc(bf16), dtda, ybuf(bf16), dtf, hbc3, woutb */
#define WS_HSB    0UL                   /* bf16 4096x4096      33554432 */
#define WS_WINB   33554432UL            /* bf16 10496x4096     85983232 */
#define WS_DSB    0UL                   /* bf16 [b][h][c][64][128] 67108864 */
#define WS_YNB    67108864UL            /* bf16 4096x4096      33554432 */
#define WS_PROJ   119537664UL           /* bf16 4096x10496     85983232 */
#define WS_XBC    205520896UL           /* bf16 4096x6144      50331648 */
#define WS_DTDA   255852544UL           /* f32  4096x64x2       2097152 */
#define WS_Y      257949696UL           /* bf16 4096x4096      33554432 */
#define WS_DTF    291504128UL           /* f32  4096x64         1048576 */
#define WS_HBC3   292552704UL           /* f32  6x6144           147456 */
#define WS_WOUTB  292700160UL           /* bf16 4096x4096      33554432 */

__device__ __forceinline__ void gl2lds16(const void* g, void* l) {
  __builtin_amdgcn_global_load_lds(
      (__attribute__((address_space(1))) unsigned int*)(uintptr_t)g,
      (__attribute__((address_space(3))) unsigned int*)(uintptr_t)l, 16, 0, 0);
}

/* ------------- merged cast fp32 -> bf16: hs + w_in(pad) + w_out --------- */
__global__ __launch_bounds__(256) void cast3_kernel(const float* __restrict__ s1,
                                                    bf16* __restrict__ d1,
                                                    const float* __restrict__ s2,
                                                    bf16* __restrict__ d2,
                                                    const float* __restrict__ s3,
                                                    bf16* __restrict__ d3,
                                                    long nsrc2, long ndst2) {
  const int bid = blockIdx.x;
  if (bid < 16384) {
    long i = ((long)bid * 256 + threadIdx.x) * 4;
    float4 v = *(const float4*)(s1 + i);
    bf16x4 o;
    o[0] = (bf16)v.x; o[1] = (bf16)v.y; o[2] = (bf16)v.z; o[3] = (bf16)v.w;
    *(bf16x4*)(d1 + i) = o;
  } else if (bid < 58368) {
    long i = ((long)(bid - 16384) * 256 + threadIdx.x) * 4;
    if (i >= ndst2) return;
    bf16x4 o;
    if (i < nsrc2) {
      float4 v = *(const float4*)(s2 + i);
      o[0] = (bf16)v.x; o[1] = (bf16)v.y; o[2] = (bf16)v.z; o[3] = (bf16)v.w;
    } else {
      o[0] = (bf16)0.f; o[1] = (bf16)0.f; o[2] = (bf16)0.f; o[3] = (bf16)0.f;
    }
    *(bf16x4*)(d2 + i) = o;
  } else {
    long i = ((long)(bid - 58368) * 256 + threadIdx.x) * 4;
    float4 v = *(const float4*)(s3 + i);
    bf16x4 o;
    o[0] = (bf16)v.x; o[1] = (bf16)v.y; o[2] = (bf16)v.z; o[3] = (bf16)v.w;
    *(bf16x4*)(d3 + i) = o;
  }
}

/* =====================================================================
   256x256 8-phase bf16 GEMM, C[M,N] = A[M,K] * B[N,K]^T
   MODE 0: C fp32.  MODE 1: C bf16 + f32 side-stores (dt cols, hbc last-3).
   ===================================================================== */
#define BARF() do { asm volatile("" ::: "memory");                    \
                    __builtin_amdgcn_s_barrier();                     \
                    asm volatile("" ::: "memory"); } while (0)
#define WAITLGKM0() do { asm volatile("s_waitcnt lgkmcnt(0)" ::: "memory"); \
                         __builtin_amdgcn_sched_barrier(0); } while (0)
#define HINTLGKM8() asm volatile("s_waitcnt lgkmcnt(8)" ::: "memory")
#define WAITVM(n) asm volatile("s_waitcnt vmcnt(" #n ")" ::: "memory")
#define PRIO1 __builtin_amdgcn_s_setprio(1)
#define PRIO0 __builtin_amdgcn_s_setprio(0)

__device__ __forceinline__ void stage_A_half(const bf16* __restrict__ A, int K,
                                             int arow, int kt, bf16* lds,
                                             int h, int tid) {
#pragma unroll
  for (int j = 0; j < 2; ++j) {
    const int r  = h * 64 + j * 128 + (tid >> 3);
    const int cb = (tid & 7) * 16;
    const int cs = cb ^ ((r & 7) << 4);
    gl2lds16(A + (size_t)(arow + r) * K + kt * 64 + (cs >> 1),
             lds + r * 64 + (cb >> 1));
  }
}
__device__ __forceinline__ void stage_B_half(const bf16* __restrict__ B, int K,
                                             int brow, int kt, bf16* lds,
                                             int h, int tid) {
#pragma unroll
  for (int j = 0; j < 2; ++j) {
    const int quarter = j * 2 + (tid >> 8);
    const int kq = tid & 255;
    const int r  = quarter * 64 + h * 32 + (kq >> 3);
    const int cb = (kq & 7) * 16;
    const int cs = cb ^ ((r & 7) << 4);
    gl2lds16(B + (size_t)(brow + r) * K + kt * 64 + (cs >> 1),
             lds + r * 64 + (cb >> 1));
  }
}

#define LDA4(p, mh) do {                                                     \
  _Pragma("unroll") for (int mt = 0; mt < 4; ++mt)                           \
  _Pragma("unroll") for (int kk = 0; kk < 2; ++kk) {                         \
    const int rr = wm * 128 + (mh) * 64 + mt * 16 + l16;                     \
    const int cc = (kk * 64 + quad * 16) ^ ((rr & 7) << 4);                  \
    a_[mt][kk] = *(const bf16x8*)((const char*)(&sA[p][rr][0]) + cc);        \
  } } while (0)

#define LDB2(p, np, barr) do {                                               \
  _Pragma("unroll") for (int nt = 0; nt < 2; ++nt)                           \
  _Pragma("unroll") for (int kk = 0; kk < 2; ++kk) {                         \
    const int rr = wn * 64 + (np) * 32 + nt * 16 + l16;                      \
    const int cc = (kk * 64 + quad * 16) ^ ((rr & 7) << 4);                  \
    barr[nt][kk] = *(const bf16x8*)((const char*)(&sB[p][rr][0]) + cc);      \
  } } while (0)

#define MFMAQ(mh, barr, nb0) do {                                            \
  _Pragma("unroll") for (int kk = 0; kk < 2; ++kk)                           \
  _Pragma("unroll") for (int mt = 0; mt < 4; ++mt)                           \
  _Pragma("unroll") for (int nt = 0; nt < 2; ++nt)                           \
    acc[(mh) * 4 + mt][(nb0) + nt] = __builtin_amdgcn_mfma_f32_16x16x32_bf16(\
        a_[mt][kk], barr[nt][kk], acc[(mh) * 4 + mt][(nb0) + nt], 0, 0, 0);  \
  } while (0)

template <int MODE>
__global__ __launch_bounds__(512, 2) void gemm256(const bf16* __restrict__ A,
                                                  const bf16* __restrict__ B,
                                                  void* __restrict__ Cv,
                                                  int M, int N, int K, int NB,
                                                  float* __restrict__ dtf,
                                                  float* __restrict__ hbc3) {
  __shared__ __align__(16) bf16 sA[2][256][64];
  __shared__ __align__(16) bf16 sB[2][256][64];

  const int tid  = threadIdx.x;
  const int wave = tid >> 6, lane = tid & 63;
  const int l16  = lane & 15, quad = lane >> 4;
  const int wm   = wave >> 2, wn = wave & 3;

  const int nwg = gridDim.x;
  const int q = nwg >> 3, r8 = nwg & 7;
  const int xcd = blockIdx.x & 7, idx = blockIdx.x >> 3;
  const int wgid = (xcd < r8 ? xcd * (q + 1) : r8 * (q + 1) + (xcd - r8) * q) + idx;
  const int mb = wgid / NB, nb = wgid - mb * NB;
  const int arow = mb * 256, brow = nb * 256;

  f32x4 acc[8][4];
#pragma unroll
  for (int i = 0; i < 8; ++i)
#pragma unroll
    for (int j = 0; j < 4; ++j) acc[i][j] = (f32x4)0.f;

  const int NT = K >> 6;

  stage_A_half(A, K, arow, 0, &sA[0][0][0], 0, tid);
  stage_B_half(B, K, brow, 0, &sB[0][0][0], 0, tid);
  stage_A_half(A, K, arow, 0, &sA[0][0][0], 1, tid);
  stage_B_half(B, K, brow, 0, &sB[0][0][0], 1, tid);
  stage_A_half(A, K, arow, 1, &sA[1][0][0], 0, tid);
  stage_B_half(B, K, brow, 1, &sB[1][0][0], 0, tid);
  stage_A_half(A, K, arow, 1, &sA[1][0][0], 1, tid);
  WAITVM(6);
  BARF();

  bf16x8 a_[4][2], b0_[2][2], b1_[2][2];

  for (int i = 0; i < NT / 2; ++i) {
    const int t1o = 2 * i + 1;
    const int t2  = (2 * i + 2 < NT) ? 2 * i + 2 : NT - 1;
    const int t3  = (2 * i + 3 < NT) ? 2 * i + 3 : NT - 1;

    LDA4(0, 0); LDB2(0, 0, b0_);
    stage_B_half(B, K, brow, t1o, &sB[1][0][0], 1, tid);
    HINTLGKM8();
    BARF(); WAITLGKM0();
    PRIO1; MFMAQ(0, b0_, 0); PRIO0;
    BARF();
    LDB2(0, 1, b1_);
    stage_A_half(A, K, arow, t2, &sA[0][0][0], 0, tid);
    BARF(); WAITLGKM0();
    PRIO1; MFMAQ(0, b1_, 2); PRIO0;
    BARF();
    LDA4(0, 1);
    stage_B_half(B, K, brow, t2, &sB[0][0][0], 0, tid);
    BARF(); WAITLGKM0();
    PRIO1; MFMAQ(1, b1_, 2); PRIO0;
    BARF();
    stage_A_half(A, K, arow, t2, &sA[0][0][0], 1, tid);
    WAITVM(6);
    BARF();
    PRIO1; MFMAQ(1, b0_, 0); PRIO0;
    BARF();
    LDA4(1, 0); LDB2(1, 0, b0_);
    stage_B_half(B, K, brow, t2, &sB[0][0][0], 1, tid);
    HINTLGKM8();
    BARF(); WAITLGKM0();
    PRIO1; MFMAQ(0, b0_, 0); PRIO0;
    BARF();
    LDB2(1, 1, b1_);
    stage_A_half(A, K, arow, t3, &sA[1][0][0], 0, tid);
    BARF(); WAITLGKM0();
    PRIO1; MFMAQ(0, b1_, 2); PRIO0;
    BARF();
    LDA4(1, 1);
    stage_B_half(B, K, brow, t3, &sB[1][0][0], 0, tid);
    BARF(); WAITLGKM0();
    PRIO1; MFMAQ(1, b1_, 2); PRIO0;
    BARF();
    stage_A_half(A, K, arow, t3, &sA[1][0][0], 1, tid);
    WAITVM(6);
    BARF();
    PRIO1; MFMAQ(1, b0_, 0); PRIO0;
    BARF();
  }
  asm volatile("s_waitcnt vmcnt(0)" ::: "memory");
  __builtin_amdgcn_s_barrier();

#pragma unroll
  for (int mt = 0; mt < 8; ++mt) {
    const int row0 = arow + wm * 128 + mt * 16 + quad * 4;
#pragma unroll
    for (int nt = 0; nt < 4; ++nt) {
      const int col = brow + wn * 64 + nt * 16 + l16;
#pragma unroll
      for (int r = 0; r < 4; ++r) {
        const float v = acc[mt][nt][r];
        const int row = row0 + r;
        if constexpr (MODE == 0) {
          ((float*)Cv)[(size_t)row * N + col] = v;
        } else {
          ((bf16*)Cv)[(size_t)row * N + col] = (bf16)v;
          const int dc = col - (II + CONVD);
          if (dc >= 0 && dc < 64) dtf[(size_t)row * 64 + dc] = v;
          const int rr = row & (LL - 1);
          if (rr >= LL - 3 && col >= II && col < II + CONVD)
            hbc3[((size_t)(row >> 11) * 3 + (rr - (LL - 3))) * CONVD + (col - II)] = v;
        }
      }
    }
  }
}

/* ---------------- conv(K=4) + SiLU, rolling-window, bf16 in/out --------- */
#define CTILE 64
__global__ __launch_bounds__(256) void conv_kernel(const bf16* __restrict__ proj,
                                                   const float* __restrict__ cw,
                                                   const float* __restrict__ cb,
                                                   bf16* __restrict__ xbc) {
  const int c   = blockIdx.x * 256 + threadIdx.x;
  const int bt0 = blockIdx.y * CTILE;
  const int t0  = bt0 & (LL - 1);
  const float4 w = *(const float4*)(cw + c * 4);
  const float bias = cb[c];
  const bf16* p = proj + (size_t)bt0 * NPAD + II + c;
  float h0, h1, h2;
  if (t0 == 0) {
    h0 = 0.f; h1 = 0.f; h2 = 0.f;
  } else {
    h0 = (float)p[-3 * (ptrdiff_t)NPAD];
    h1 = (float)p[-2 * (ptrdiff_t)NPAD];
    h2 = (float)p[-(ptrdiff_t)NPAD];
  }
  bf16* q = xbc + (size_t)bt0 * CONVD + c;
#pragma unroll 8
  for (int t = 0; t < CTILE; ++t) {
    const float cur = (float)p[(ptrdiff_t)t * NPAD];
    const float acc = bias + h0 * w.x + h1 * w.y + h2 * w.z + cur * w.w;
    q[(size_t)t * CONVD] = (bf16)(acc / (1.f + __expf(-acc)));
    h0 = h1; h1 = h2; h2 = cur;
  }
}

/* -------- merged: dtda (from f32 side-buffer) + conv_state copy --------- */
__global__ __launch_bounds__(256) void dtcs_kernel(const float* __restrict__ dtf,
                                                   const float* __restrict__ hbc3,
                                                   const float* __restrict__ dt_bias,
                                                   const float* __restrict__ A_log,
                                                   float* __restrict__ dtda,
                                                   float* __restrict__ outp) {
  const int bid = blockIdx.x;
  if (bid < 1024) {
    const int idx = bid * 256 + threadIdx.x;
    const int h = idx & 63;
    const float z = dtf[idx] + dt_bias[h];
    const float sp = (z > 20.f) ? z : log1pf(__expf(z));
    const float a = -__expf(A_log[h]);
    float2 o; o.x = sp; o.y = __expf(sp * a);
    *(float2*)(dtda + (size_t)idx * 2) = o;
  } else {
    const int idx = (bid - 1024) * 256 + threadIdx.x;
    if (idx >= BB * CONVD * 3) return;
    const int b = idx / (CONVD * 3);
    const int r = idx - b * CONVD * 3;
    const int c = r / 3, j = r - c * 3;
    outp[idx] = hbc3[((size_t)b * 3 + j) * CONVD + c];
  }
}

/* =============== chunked SSD scan =============== */
#define SCAN_DECODE()                                                  \
  const int lin = blockIdx.x;                                          \
  const int hh  = (lin >> 3) & 7;                                      \
  const int id  = (lin & 7) | ((lin >> 6) << 3);                       \
  const int g   = id >> 6, c = (id >> 1) & 31, b = id & 1;             \
  const int h   = g * 8 + hh;

/* chunkA: per (b,h,c): G=C·B^T, W=mask(G), Yintra=W·X (bf16), dS=(wX)^T·B */
__global__ __launch_bounds__(256) void chunkA_kernel(const bf16* __restrict__ xbc,
                                                     const float* __restrict__ dtda,
                                                     const float* __restrict__ A_log,
                                                     bf16* __restrict__ ybuf,
                                                     bf16* __restrict__ dsb) {
  SCAN_DECODE();
  const int tid = threadIdx.x;
  const int wave = tid >> 6, lane = tid & 63;
  const int l16 = lane & 15, quad = lane >> 4;

  __shared__ __align__(16) bf16 CsBt[8192];
  __shared__ __align__(16) bf16 Bs[64][128];
  __shared__ __align__(16) bf16 Xt[64][64];
  __shared__ __align__(16) bf16 Ws[64][64];
  __shared__ float cums[64], dtps[64], wls[64];

  bf16 (*Cs)[128] = (bf16(*)[128])CsBt;
  bf16 (*Bt)[64]  = (bf16(*)[64])CsBt;

  const size_t rowbase = ((size_t)b * LL + (size_t)c * CT) * CONVD;

  {
    const int r0 = wave * 16;
    const bf16* gC = xbc + rowbase + (II + GN_) + g * 128;
    const bf16* gB = xbc + rowbase + II + g * 128;
#pragma unroll
    for (int j = 0; j < 4; ++j) {
      const int r  = r0 + j * 4 + (lane >> 4);
      const int ch = (lane & 15) ^ (r & 15);
      gl2lds16(gC + (size_t)r * CONVD + ch * 8, &Cs[r0 + j * 4][0]);
      gl2lds16(gB + (size_t)r * CONVD + ch * 8, &Bs[r0 + j * 4][0]);
    }
  }
  {
    const int j = tid >> 2, p0 = (tid & 3) * 16;
    const bf16* gpX = xbc + rowbase + (size_t)j * CONVD + h * 64 + p0;
#pragma unroll
    for (int k = 0; k < 2; ++k) {
      bf16x8 v = *(const bf16x8*)(gpX + k * 8);
#pragma unroll
      for (int e = 0; e < 8; ++e) {
        const int pp = p0 + k * 8 + e;
        Xt[pp][(((j >> 3) ^ (pp & 7)) * 8) + (j & 7)] = v[e];
      }
    }
  }
  if (wave == 0) {
    const float Ah = -__expf(A_log[h]);
    float2 dd = *(const float2*)(dtda + ((size_t)((b * LL + c * CT + lane)) * 64 + h) * 2);
    float s = dd.x * Ah;
#pragma unroll
    for (int d = 1; d < 64; d <<= 1) {
      float v = __shfl_up(s, d);
      if (lane >= d) s += v;
    }
    const float tot = __shfl(s, 63);
    cums[lane] = s;
    dtps[lane] = dd.x;
    wls[lane]  = __expf(tot - s) * dd.x;
  }
  __syncthreads();

  const int mrow = wave * 16 + l16;
  {
    f32x4 accg[4];
#pragma unroll
    for (int nt = 0; nt < 4; ++nt) accg[nt] = (f32x4)0.f;
#pragma unroll
    for (int k0 = 0; k0 < 128; k0 += 32) {
      bf16x8 af = *(const bf16x8*)&Cs[mrow][(((k0 >> 3) + quad) ^ (mrow & 15)) * 8];
#pragma unroll
      for (int nt = 0; nt < 4; ++nt) {
        const int nrow = nt * 16 + l16;
        bf16x8 bfr = *(const bf16x8*)&Bs[nrow][(((k0 >> 3) + quad) ^ (nrow & 15)) * 8];
        accg[nt] = __builtin_amdgcn_mfma_f32_16x16x32_bf16(af, bfr, accg[nt], 0, 0, 0);
      }
    }
#pragma unroll
    for (int nt = 0; nt < 4; ++nt) {
      const int j = nt * 16 + l16;
#pragma unroll
      for (int r = 0; r < 4; ++r) {
        const int i = wave * 16 + quad * 4 + r;
        float v = 0.f;
        if (j <= i) v = accg[nt][r] * __expf(cums[i] - cums[j]) * dtps[j];
        Ws[i][(((j >> 3) ^ (i & 7)) * 8) + (j & 7)] = (bf16)v;
      }
    }
  }
  __syncthreads();

  {
    const int n = tid >> 1, j0 = (tid & 1) * 32;
#pragma unroll
    for (int k = 0; k < 4; ++k) {
      bf16x8 v;
#pragma unroll
      for (int e = 0; e < 8; ++e) {
        const int j = j0 + k * 8 + e;
        v[e] = Bs[j][(((n >> 3) ^ (j & 15)) * 8) + (n & 7)];
      }
      *(bf16x8*)(&Bt[n][((((j0 + k * 8) >> 3) ^ (n & 7)) * 8)]) = v;
    }
  }
  __syncthreads();

  f32x4 accy[4];
#pragma unroll
  for (int pt = 0; pt < 4; ++pt) accy[pt] = (f32x4)0.f;
#pragma unroll
  for (int k0 = 0; k0 < 64; k0 += 32) {
    bf16x8 af = *(const bf16x8*)&Ws[mrow][(((k0 >> 3) + quad) ^ (mrow & 7)) * 8];
#pragma unroll
    for (int pt = 0; pt < 4; ++pt) {
      const int prow = pt * 16 + l16;
      bf16x8 bfr = *(const bf16x8*)&Xt[prow][(((k0 >> 3) + quad) ^ (prow & 7)) * 8];
      accy[pt] = __builtin_amdgcn_mfma_f32_16x16x32_bf16(af, bfr, accy[pt], 0, 0, 0);
    }
  }

  f32x4 accs[8];
#pragma unroll
  for (int nt = 0; nt < 8; ++nt) accs[nt] = (f32x4)0.f;
#pragma unroll
  for (int k0 = 0; k0 < 64; k0 += 32) {
    bf16x8 axr = *(const bf16x8*)&Xt[mrow][(((k0 >> 3) + quad) ^ (mrow & 7)) * 8];
    bf16x8 ax;
#pragma unroll
    for (int e = 0; e < 8; ++e)
      ax[e] = (bf16)((float)axr[e] * wls[k0 + quad * 8 + e]);
#pragma unroll
    for (int nt = 0; nt < 8; ++nt) {
      const int nrow = nt * 16 + l16;
      bf16x8 bfr = *(const bf16x8*)&Bt[nrow][(((k0 >> 3) + quad) ^ (nrow & 7)) * 8];
      accs[nt] = __builtin_amdgcn_mfma_f32_16x16x32_bf16(ax, bfr, accs[nt], 0, 0, 0);
    }
  }

#pragma unroll
  for (int pt = 0; pt < 4; ++pt) {
#pragma unroll
    for (int r = 0; r < 4; ++r) {
      const int i = wave * 16 + quad * 4 + r;
      ybuf[((size_t)(b * LL + c * CT + i)) * II + h * 64 + pt * 16 + l16] = (bf16)accy[pt][r];
    }
  }
  const size_t dbase = (((size_t)(b * HH + h)) * NC + c) * (CT * NN);
#pragma unroll
  for (int nt = 0; nt < 8; ++nt) {
#pragma unroll
    for (int r = 0; r < 4; ++r) {
      const int p = wave * 16 + quad * 4 + r;
      dsb[dbase + (size_t)p * NN + nt * 16 + l16] = (bf16)accs[nt][r];
    }
  }
}

/* chain: serial over 32 chunks; in-place dS -> S_prev; final_state -> out */
__global__ __launch_bounds__(256) void chain_kernel(const float* __restrict__ dtda,
                                                    const float* __restrict__ A_log,
                                                    bf16* __restrict__ dsb,
                                                    float* __restrict__ fst) {
  const int blk = blockIdx.x;           /* ((b*64 + h)*4 + qtr) */
  const int b = blk >> 8, h = (blk >> 2) & 63, qtr = blk & 3;
  const int tid = threadIdx.x, wave = tid >> 6, lane = tid & 63;
  __shared__ float DcL[NC];

  const float Ah = -__expf(A_log[h]);
#pragma unroll
  for (int cc = 0; cc < 8; ++cc) {
    const int c = wave * 8 + cc;
    float2 dd = *(const float2*)(dtda + ((size_t)(b * LL + c * CT + lane) * 64 + h) * 2);
    float a = dd.x * Ah;
#pragma unroll
    for (int m = 1; m <= 32; m <<= 1) a += __shfl_xor(a, m);
    if (lane == 0) DcL[c] = __expf(a);
  }

  const int local = qtr * 2048 + tid * 8;
  const size_t base = ((size_t)(b * HH + h)) * NC * (CT * NN) + local;
  float s[8];
#pragma unroll
  for (int e = 0; e < 8; ++e) s[e] = 0.f;

  bf16x8 d0 = *(const bf16x8*)(dsb + base);
  __syncthreads();

  for (int c = 0; c < NC; ++c) {
    bf16* p = dsb + base + (size_t)c * (CT * NN);
    bf16x8 dn;
    if (c + 1 < NC) dn = *(const bf16x8*)(p + (CT * NN));
    const float dc = DcL[c];
    bf16x8 o0;
#pragma unroll
    for (int e = 0; e < 8; ++e) o0[e] = (bf16)s[e];
    *(bf16x8*)(p) = o0;
#pragma unroll
    for (int e = 0; e < 8; ++e) s[e] = s[e] * dc + (float)d0[e];
    d0 = dn;
  }
  float* fp = fst + ((size_t)(b * HH + h)) * (PP * NN) + local;
#pragma unroll
  for (int k = 0; k < 2; ++k) {
    float4 v = { s[k * 4], s[k * 4 + 1], s[k * 4 + 2], s[k * 4 + 3] };
    *(float4*)(fp + k * 4) = v;
  }
}

/* chunkBN: fused chunkB + groupnorm + silu(gate) -> ynb (bf16)
   block = (b,c,g): 8 waves = 8 heads of the group.
   y = Yintra + exp(cum_i)*(C·S_prev^T) + D*x  (f32 in regs)
   -> cross-wave sum-of-squares -> rstd -> LDS repack -> *nw*silu(gate)   */
__global__ __launch_bounds__(512) void chunkBN_kernel(const bf16* __restrict__ xbc,
                                                      const float* __restrict__ dtda,
                                                      const float* __restrict__ A_log,
                                                      const float* __restrict__ Dv,
                                                      const bf16* __restrict__ spb,
                                                      const bf16* __restrict__ ybi,
                                                      const bf16* __restrict__ proj,
                                                      const float* __restrict__ nw,
                                                      bf16* __restrict__ ynb) {
  const int lin = blockIdx.x;
  const int g = lin >> 6, c = (lin >> 1) & 31, b = lin & 1;
  const int tid = threadIdx.x;
  const int w = tid >> 6, lane = tid & 63;
  const int l16 = lane & 15, quad = lane >> 4;
  const int h = g * 8 + w;

  __shared__ __align__(16) char LB[147456];   /* Cs 16K @0, Sp 8x16K @16384; yls f32[64][516] overlay */
  __shared__ float sums[8][64];
  __shared__ float es[64];
  __shared__ float rstd[64];

  bf16 (*Cs)[128] = (bf16(*)[128])LB;
  bf16 (*Sp)[128] = (bf16(*)[128])(LB + 16384 + (size_t)w * 16384);

  const size_t rowbase = ((size_t)b * LL + (size_t)c * CT) * CONVD;
  {
    const bf16* gC = xbc + rowbase + (II + GN_) + g * 128;
#pragma unroll
    for (int j = 0; j < 2; ++j) {
      const int r  = w * 8 + j * 4 + (lane >> 4);
      const int ch = (lane & 15) ^ (r & 15);
      gl2lds16(gC + (size_t)r * CONVD + ch * 8, LB + (w * 8 + j * 4) * 256);
    }
    const bf16* gS = spb + (((size_t)(b * HH + h)) * NC + c) * (CT * NN);
#pragma unroll
    for (int j = 0; j < 16; ++j) {
      const int r  = j * 4 + (lane >> 4);
      const int ch = (lane & 15) ^ (r & 15);
      gl2lds16(gS + (size_t)r * NN + ch * 8, LB + 16384 + w * 16384 + j * 1024);
    }
  }
  if (w == 0) {
    const float Ah = -__expf(A_log[h]);   /* cumsum is head-independent? no: per-h; but es only needs h of wave0? */
    /* es depends on h through dtda[...][h]*Ah -- all heads share (b,c) rows but
       have DIFFERENT h. es must be per-head! -> compute per-wave into sums area
       first, then copy. Simpler: every wave computes its own es into esw[w][64]. */
  }
  /* per-head es: cumsum over the 64 rows for THIS head */
  __shared__ float esw[8][64];
  {
    const float Ah = -__expf(A_log[h]);
    float2 dd = *(const float2*)(dtda + ((size_t)(b * LL + c * CT + lane) * 64 + h) * 2);
    float s = dd.x * Ah;
#pragma unroll
    for (int d = 1; d < 64; d <<= 1) {
      float v = __shfl_up(s, d);
      if (lane >= d) s += v;
    }
    esw[w][lane] = __expf(s);
  }
  __syncthreads();

  f32x4 acc[4][4];
#pragma unroll
  for (int it = 0; it < 4; ++it)
#pragma unroll
    for (int pt = 0; pt < 4; ++pt) acc[it][pt] = (f32x4)0.f;

#pragma unroll
  for (int k0 = 0; k0 < 128; k0 += 32) {
    bf16x8 af[4], bfr[4];
#pragma unroll
    for (int it = 0; it < 4; ++it) {
      const int rr = it * 16 + l16;
      af[it]  = *(const bf16x8*)&Cs[rr][(((k0 >> 3) + quad) ^ (rr & 15)) * 8];
      bfr[it] = *(const bf16x8*)&Sp[rr][(((k0 >> 3) + quad) ^ (rr & 15)) * 8];
    }
#pragma unroll
    for (int it = 0; it < 4; ++it)
#pragma unroll
      for (int pt = 0; pt < 4; ++pt)
        acc[it][pt] = __builtin_amdgcn_mfma_f32_16x16x32_bf16(af[it], bfr[pt], acc[it][pt], 0, 0, 0);
  }

  /* epilogue: finalize y in regs */
  const float Dh = Dv[h];
  const size_t grow0 = (size_t)b * LL + (size_t)c * CT;
#pragma unroll
  for (int it = 0; it < 4; ++it)
#pragma unroll
    for (int pt = 0; pt < 4; ++pt)
#pragma unroll
      for (int r = 0; r < 4; ++r) {
        const int row = it * 16 + quad * 4 + r;
        const int colh = pt * 16 + l16;
        const size_t gr = grow0 + row;
        acc[it][pt][r] = acc[it][pt][r] * esw[w][row]
                       + (float)ybi[gr * II + h * 64 + colh]
                       + Dh * (float)xbc[gr * CONVD + h * 64 + colh];
      }

  /* per-row sum of squares (within head), reduce over l16, publish */
  float ssv[4][4];
#pragma unroll
  for (int it = 0; it < 4; ++it)
#pragma unroll
    for (int r = 0; r < 4; ++r) {
      float s = 0.f;
#pragma unroll
      for (int pt = 0; pt < 4; ++pt) s += acc[it][pt][r] * acc[it][pt][r];
#pragma unroll
      for (int m = 1; m <= 8; m <<= 1) s += __shfl_xor(s, m);
      ssv[it][r] = s;
    }
  if (l16 == 0) {
#pragma unroll
    for (int it = 0; it < 4; ++it)
#pragma unroll
      for (int r = 0; r < 4; ++r)
        sums[w][it * 16 + quad * 4 + r] = ssv[it][r];
  }
  __syncthreads();   /* Sp/Cs reads done; sums complete */

  if (tid < 64) {
    float tot = 0.f;
#pragma unroll
    for (int ww = 0; ww < 8; ++ww) tot += sums[ww][tid];
    rstd[tid] = rsqrtf(tot * (1.f / 512.f) + 1e-5f);
  }
  float* yls = (float*)LB;   /* [64][516] f32, overlays Cs+Sp */
#pragma unroll
  for (int it = 0; it < 4; ++it)
#pragma unroll
    for (int pt = 0; pt < 4; ++pt)
#pragma unroll
      for (int r = 0; r < 4; ++r)
        yls[(it * 16 + quad * 4 + r) * 516 + w * 64 + pt * 16 + l16] = acc[it][pt][r];
  __syncthreads();

  /* repack: normalize, gate, write coalesced bf16 */
  {
    const int row = tid >> 3, ch = tid & 7;
    const size_t gr = grow0 + row;
    const float rs = rstd[row];
#pragma unroll
    for (int k = 0; k < 4; ++k) {
      const int col = ch * 16 + k * 128;
      const float* yl = yls + (size_t)row * 516 + col;
      bf16x8 gv0 = *(const bf16x8*)(proj + gr * NPAD + g * 512 + col);
      bf16x8 gv1 = *(const bf16x8*)(proj + gr * NPAD + g * 512 + col + 8);
      bf16x8 o0, o1;
#pragma unroll
      for (int e = 0; e < 8; ++e) {
        const float gf0 = (float)gv0[e];
        const float gf1 = (float)gv1[e];
        const float v0 = yl[e]     * rs * nw[g * 512 + col + e]     * (gf0 / (1.f + __expf(-gf0)));
        const float v1 = yl[e + 8] * rs * nw[g * 512 + col + e + 8] * (gf1 / (1.f + __expf(-gf1)));
        o0[e] = (bf16)v0; o1[e] = (bf16)v1;
      }
      *(bf16x8*)(ynb + gr * II + g * 512 + col)     = o0;
      *(bf16x8*)(ynb + gr * II + g * 512 + col + 8) = o1;
    }
  }
}

extern "C" void kernel_launch(void* const* d_in, const int* in_sizes, int n_in,
                              void* d_out, int out_size, void* d_ws, size_t ws_size,
                              hipStream_t stream) {
  const float* hs      = (const float*)d_in[0];
  const float* w_in    = (const float*)d_in[1];
  const float* cw      = (const float*)d_in[2];
  const float* cb      = (const float*)d_in[3];
  const float* dt_bias = (const float*)d_in[4];
  const float* A_log   = (const float*)d_in[5];
  const float* Dv      = (const float*)d_in[6];
  const float* nw      = (const float*)d_in[7];
  const float* w_out   = (const float*)d_in[8];

  char* ws = (char*)d_ws;
  bf16*  hsb   = (bf16*)(ws + WS_HSB);
  bf16*  winb  = (bf16*)(ws + WS_WINB);
  bf16*  dsb   = (bf16*)(ws + WS_DSB);
  bf16*  ynb   = (bf16*)(ws + WS_YNB);
  bf16*  proj  = (bf16*)(ws + WS_PROJ);
  bf16*  xbc   = (bf16*)(ws + WS_XBC);
  float* dtda  = (float*)(ws + WS_DTDA);
  bf16*  ybuf  = (bf16*)(ws + WS_Y);
  float* dtf   = (float*)(ws + WS_DTF);
  float* hbc3  = (float*)(ws + WS_HBC3);
  bf16*  woutb = (bf16*)(ws + WS_WOUTB);

  float* outp = (float*)d_out;

  cast3_kernel<<<74752, 256, 0, stream>>>(hs, hsb, w_in, winb, w_out, woutb,
                                          (long)PROJD * DM, (long)NPAD * DM);

  gemm256<1><<<(BT / 256) * (NPAD / 256), 512, 0, stream>>>(
      hsb, winb, proj, BT, NPAD, DM, NPAD / 256, dtf, hbc3);

  conv_kernel<<<dim3(CONVD / 256, BT / CTILE), 256, 0, stream>>>(proj, cw, cb, xbc);
  dtcs_kernel<<<1168, 256, 0, stream>>>(dtf, hbc3, dt_bias, A_log, dtda, outp + OUT_OFS_CONV);

  chunkA_kernel<<<4096, 256, 0, stream>>>(xbc, dtda, A_log, ybuf, dsb);
  chain_kernel<<<BB * HH * 4, 256, 0, stream>>>(dtda, A_log, dsb, outp + OUT_OFS_STATE);
  chunkBN_kernel<<<512, 512, 0, stream>>>(xbc, dtda, A_log, Dv, dsb, ybuf, proj, nw, ynb);

  gemm256<0><<<(BT / 256) * (DM / 256), 512, 0, stream>>>(
      ynb, woutb, outp, BT, DM, II, DM / 256, nullptr, nullptr);
}